// Round 1
// baseline (230.349 us; speedup 1.0000x reference)
//
#include <hip/hip_runtime.h>
#include <hip/hip_bf16.h>
#include <stdint.h>

typedef unsigned short u16;
typedef __attribute__((ext_vector_type(8))) short short8;
typedef __attribute__((ext_vector_type(4))) float f32x4;

// ws layout (bytes): [0,8M) x_bf16 [8M,16M) Wt(4x1Mx2B) [16M,24M) q [24M,32M) k
// [32M,40M) v [40M,48M) y   -- requires ws_size >= 48MB
static __device__ __forceinline__ u16 f2bf(float f) {
  unsigned u = __builtin_bit_cast(unsigned, f);
  u += 0x7fffu + ((u >> 16) & 1u);
  return (u16)(u >> 16);
}

static __device__ __forceinline__ void gload16(const u16* g, u16* l) {
  __builtin_amdgcn_global_load_lds(
      (__attribute__((address_space(1))) void*)const_cast<u16*>(g),
      (__attribute__((address_space(3))) void*)l, 16, 0, 0);
}

// ---------------- x fp32 -> bf16 ----------------
__global__ __launch_bounds__(256) void cvt_x_kernel(const float* __restrict__ x,
                                                    u16* __restrict__ xb) {
  size_t i = (size_t)blockIdx.x * 256 + threadIdx.x;  // 8 floats per thread
  const float4* xp = (const float4*)x + i * 2;
  float4 a = xp[0], b = xp[1];
  union { u16 u[8]; int4 v; } r;
  r.u[0] = f2bf(a.x); r.u[1] = f2bf(a.y); r.u[2] = f2bf(a.z); r.u[3] = f2bf(a.w);
  r.u[4] = f2bf(b.x); r.u[5] = f2bf(b.y); r.u[6] = f2bf(b.z); r.u[7] = f2bf(b.w);
  *(int4*)(xb + i * 8) = r.v;
}

// ---------------- W [k][n] fp32 -> Wt [n][k] bf16 (x4 weights) ----------------
__global__ __launch_bounds__(256) void wtrans_kernel(const float* __restrict__ Wq,
                                                     const float* __restrict__ Wk,
                                                     const float* __restrict__ Wv,
                                                     const float* __restrict__ Wp,
                                                     u16* __restrict__ wt) {
  __shared__ float tile[64][65];
  int wz = blockIdx.z;
  const float* W = (wz == 0) ? Wq : (wz == 1) ? Wk : (wz == 2) ? Wv : Wp;
  int n0 = blockIdx.x * 64, k0 = blockIdx.y * 64;
  int tx = threadIdx.x & 63, ty = threadIdx.x >> 6;
#pragma unroll
  for (int r = 0; r < 16; ++r)
    tile[ty + 4 * r][tx] = W[(size_t)(k0 + ty + 4 * r) * 1024 + n0 + tx];
  __syncthreads();
  u16* dst = wt + (size_t)wz * 1024 * 1024;
#pragma unroll
  for (int r = 0; r < 16; ++r) {
    int n = ty + 4 * r;
    dst[(size_t)(n0 + n) * 1024 + k0 + tx] = f2bf(tile[tx][n]);
  }
}

// ---------------- 128x128 MFMA GEMM, BK=64, global_load_lds staging ----------------
// EPI=0: QKV epilogue -> scatter bf16 into [B,H,T,D] q/k/v with per-column bias
// EPI=1: proj epilogue -> fp32 out[m*1024+n] + bias
template <int EPI>
__global__ __launch_bounds__(256) void gemm128_kernel(
    const u16* __restrict__ A, const u16* __restrict__ Bt, int Kdim,
    u16* __restrict__ qd, u16* __restrict__ kd, u16* __restrict__ vd,
    const float* __restrict__ bq, const float* __restrict__ bk,
    const float* __restrict__ bv, float* __restrict__ outf,
    const float* __restrict__ bias1) {
  __shared__ u16 Alds[128 * 64];
  __shared__ u16 Blds[128 * 64];
  int tid = threadIdx.x;
  int lane = tid & 63, w = tid >> 6;
  int l15 = lane & 15, lg = lane >> 4;
  int m0 = blockIdx.y * 128, n0 = blockIdx.x * 128;
  int wm = (w >> 1) * 64, wn = (w & 1) * 64;
  int srow = lane >> 3, scol = (lane & 7) * 8;
  f32x4 acc[4][4] = {};
  for (int kt = 0; kt < Kdim; kt += 64) {
#pragma unroll
    for (int j = 0; j < 4; ++j) {
      int issue = w * 4 + j;
      int row = issue * 8 + srow;
      gload16(&A[(size_t)(m0 + row) * Kdim + kt + scol], &Alds[issue * 512]);
      gload16(&Bt[(size_t)(n0 + row) * Kdim + kt + scol], &Blds[issue * 512]);
    }
    __syncthreads();
#pragma unroll
    for (int kk = 0; kk < 2; ++kk) {
      short8 a[4], b[4];
#pragma unroll
      for (int mt = 0; mt < 4; ++mt)
        a[mt] = *(const short8*)&Alds[(wm + mt * 16 + l15) * 64 + kk * 32 + lg * 8];
#pragma unroll
      for (int nt = 0; nt < 4; ++nt)
        b[nt] = *(const short8*)&Blds[(wn + nt * 16 + l15) * 64 + kk * 32 + lg * 8];
#pragma unroll
      for (int mt = 0; mt < 4; ++mt)
#pragma unroll
        for (int nt = 0; nt < 4; ++nt)
          acc[mt][nt] = __builtin_amdgcn_mfma_f32_16x16x32_bf16(a[mt], b[nt],
                                                                acc[mt][nt], 0, 0, 0);
    }
    __syncthreads();
  }
  if (EPI == 0) {
#pragma unroll
    for (int nt = 0; nt < 4; ++nt) {
      int n = n0 + wn + nt * 16 + l15;
      int wi = n >> 10, nn = n & 1023, h = nn >> 6, d = nn & 63;
      u16* dst = (wi == 0) ? qd : (wi == 1) ? kd : vd;
      const float* bb = (wi == 0) ? bq : (wi == 1) ? bk : bv;
      float bval = bb[nn];
#pragma unroll
      for (int mt = 0; mt < 4; ++mt) {
#pragma unroll
        for (int i = 0; i < 4; ++i) {
          int m = m0 + wm + mt * 16 + lg * 4 + i;
          int mb = m >> 11, t = m & 2047;
          dst[((size_t)(mb * 16 + h) * 2048 + t) * 64 + d] = f2bf(acc[mt][nt][i] + bval);
        }
      }
    }
  } else {
#pragma unroll
    for (int nt = 0; nt < 4; ++nt) {
      int n = n0 + wn + nt * 16 + l15;
      float bval = bias1[n];
#pragma unroll
      for (int mt = 0; mt < 4; ++mt) {
#pragma unroll
        for (int i = 0; i < 4; ++i) {
          int m = m0 + wm + mt * 16 + lg * 4 + i;
          outf[(size_t)m * 1024 + n] = acc[mt][nt][i] + bval;
        }
      }
    }
  }
}

// ---------------- causal flash attention, bf16 MFMA, fp32 softmax ----------------
// block: 128 q-rows (4 waves x 32 rows), KV tiles of 64. K and V^T in
// XOR-swizzled LDS (byte ^= (row&7)<<4 kills the 128B-row-stride conflict).
__global__ __launch_bounds__(256) void fattn_kernel(const u16* __restrict__ qb,
                                                    const u16* __restrict__ kb,
                                                    const u16* __restrict__ vb,
                                                    u16* __restrict__ y) {
  __shared__ u16 Klds[64 * 64];
  __shared__ u16 Vlds[64 * 64];   // V transposed: [d][kv]
  __shared__ u16 Plds[4][32 * 64];
  const float LOG2E = 1.44269504088896340736f;
  int tid = threadIdx.x, lane = tid & 63, w = tid >> 6;
  int l15 = lane & 15, lg = lane >> 4;
  int bh = blockIdx.y;
  int q0 = blockIdx.x * 128;
  int qw = q0 + w * 32;
  size_t base = (size_t)bh * 2048 * 64;
  short8 qf[2][2];
#pragma unroll
  for (int mt = 0; mt < 2; ++mt)
#pragma unroll
    for (int kk = 0; kk < 2; ++kk)
      qf[mt][kk] = *(const short8*)&qb[base + (size_t)(qw + mt * 16 + l15) * 64 + kk * 32 + lg * 8];
  f32x4 o[2][4] = {};
  float mrow[2][4], lrow[2][4];
#pragma unroll
  for (int mt = 0; mt < 2; ++mt)
#pragma unroll
    for (int i = 0; i < 4; ++i) { mrow[mt][i] = -__builtin_inff(); lrow[mt][i] = 0.f; }
  int vd = tid & 63, vg = tid >> 6;
  int jmax = 2 * blockIdx.x + 1;
  for (int j = 0; j <= jmax; ++j) {
    int k0 = j * 64;
    // stage K tile [kv][d], swizzled
#pragma unroll
    for (int it = 0; it < 2; ++it) {
      int chunk = tid + it * 256;
      int row = chunk >> 3, c8 = (chunk & 7) * 8;
      int4 val = *(const int4*)&kb[base + (size_t)(k0 + row) * 64 + c8];
      int addr = (row * 128 + c8 * 2) ^ ((row & 7) << 4);
      *(int4*)((char*)Klds + addr) = val;
    }
    // stage V transposed [d][kv], swizzled
#pragma unroll
    for (int it = 0; it < 2; ++it) {
      int kv0 = vg * 8 + it * 32;
      short8 pv;
#pragma unroll
      for (int jj = 0; jj < 8; ++jj)
        pv[jj] = (short)vb[base + (size_t)(k0 + kv0 + jj) * 64 + vd];
      int addr = (vd * 128 + kv0 * 2) ^ ((vd & 7) << 4);
      *(short8*)((char*)Vlds + addr) = pv;
    }
    __syncthreads();
    if (k0 <= qw + 31) {   // wave-uniform skip of fully-masked tiles
      f32x4 s[2][4] = {};
#pragma unroll
      for (int kk = 0; kk < 2; ++kk) {
        short8 bk_[4];
#pragma unroll
        for (int nt = 0; nt < 4; ++nt) {
          int row = nt * 16 + l15;
          int addr = (row * 128 + (kk * 32 + lg * 8) * 2) ^ ((row & 7) << 4);
          bk_[nt] = *(const short8*)((char*)Klds + addr);
        }
#pragma unroll
        for (int mt = 0; mt < 2; ++mt)
#pragma unroll
          for (int nt = 0; nt < 4; ++nt)
            s[mt][nt] = __builtin_amdgcn_mfma_f32_16x16x32_bf16(qf[mt][kk], bk_[nt],
                                                                s[mt][nt], 0, 0, 0);
      }
      bool diag = (k0 + 63 > qw);
#pragma unroll
      for (int mt = 0; mt < 2; ++mt) {
#pragma unroll
        for (int i = 0; i < 4; ++i) {
          int qr = qw + mt * 16 + lg * 4 + i;
          float vmax = -__builtin_inff();
#pragma unroll
          for (int nt = 0; nt < 4; ++nt) {
            float sv = s[mt][nt][i] * 0.125f;
            if (diag && (k0 + nt * 16 + l15 > qr)) sv = -__builtin_inff();
            s[mt][nt][i] = sv;
            vmax = fmaxf(vmax, sv);
          }
#pragma unroll
          for (int off = 1; off < 16; off <<= 1)
            vmax = fmaxf(vmax, __shfl_xor(vmax, off));
          float mnew = fmaxf(mrow[mt][i], vmax);
          float scale = exp2f((mrow[mt][i] - mnew) * LOG2E);
          mrow[mt][i] = mnew;
          float rsum = 0.f;
#pragma unroll
          for (int nt = 0; nt < 4; ++nt) {
            float p = exp2f((s[mt][nt][i] - mnew) * LOG2E);
            s[mt][nt][i] = p;
            rsum += p;
          }
#pragma unroll
          for (int off = 1; off < 16; off <<= 1)
            rsum += __shfl_xor(rsum, off);
          lrow[mt][i] = lrow[mt][i] * scale + rsum;
#pragma unroll
          for (int dn = 0; dn < 4; ++dn) o[mt][dn][i] *= scale;
        }
        // write P rows (bf16) into per-wave swizzled LDS
#pragma unroll
        for (int nt = 0; nt < 4; ++nt)
#pragma unroll
          for (int i = 0; i < 4; ++i) {
            int row = mt * 16 + lg * 4 + i, col = nt * 16 + l15;
            int addr = (row * 128 + col * 2) ^ ((row & 7) << 4);
            *(u16*)((char*)Plds[w] + addr) = f2bf(s[mt][nt][i]);
          }
      }
      // O += P * V
#pragma unroll
      for (int kk = 0; kk < 2; ++kk) {
        short8 ap[2], bv_[4];
#pragma unroll
        for (int mt = 0; mt < 2; ++mt) {
          int row = mt * 16 + l15;
          int addr = (row * 128 + (kk * 32 + lg * 8) * 2) ^ ((row & 7) << 4);
          ap[mt] = *(const short8*)((char*)Plds[w] + addr);
        }
#pragma unroll
        for (int dn = 0; dn < 4; ++dn) {
          int row = dn * 16 + l15;
          int addr = (row * 128 + (kk * 32 + lg * 8) * 2) ^ ((row & 7) << 4);
          bv_[dn] = *(const short8*)((char*)Vlds + addr);
        }
#pragma unroll
        for (int mt = 0; mt < 2; ++mt)
#pragma unroll
          for (int dn = 0; dn < 4; ++dn)
            o[mt][dn] = __builtin_amdgcn_mfma_f32_16x16x32_bf16(ap[mt], bv_[dn],
                                                                o[mt][dn], 0, 0, 0);
      }
    }
    __syncthreads();
  }
  // normalize + write y [B,T,C] bf16
  int mb = bh >> 4, h = bh & 15;
#pragma unroll
  for (int mt = 0; mt < 2; ++mt)
#pragma unroll
    for (int i = 0; i < 4; ++i) {
      int qr = qw + mt * 16 + lg * 4 + i;
      float inv = 1.f / lrow[mt][i];
      size_t rb = ((size_t)(mb * 2048 + qr)) * 1024 + (size_t)h * 64;
#pragma unroll
      for (int dn = 0; dn < 4; ++dn)
        y[rb + dn * 16 + l15] = f2bf(o[mt][dn][i] * inv);
    }
}

extern "C" void kernel_launch(void* const* d_in, const int* in_sizes, int n_in,
                              void* d_out, int out_size, void* d_ws, size_t ws_size,
                              hipStream_t stream) {
  const float* x  = (const float*)d_in[0];
  const float* Wq = (const float*)d_in[1];
  const float* bq = (const float*)d_in[2];
  const float* Wk = (const float*)d_in[3];
  const float* bk = (const float*)d_in[4];
  const float* Wv = (const float*)d_in[5];
  const float* bv = (const float*)d_in[6];
  const float* Wp = (const float*)d_in[7];
  const float* bp = (const float*)d_in[8];
  float* out = (float*)d_out;
  char* ws = (char*)d_ws;
  u16* xb   = (u16*)(ws);
  u16* wt   = (u16*)(ws + ((size_t)8 << 20));
  u16* qbuf = (u16*)(ws + ((size_t)16 << 20));
  u16* kbuf = (u16*)(ws + ((size_t)24 << 20));
  u16* vbuf = (u16*)(ws + ((size_t)32 << 20));
  u16* ybuf = (u16*)(ws + ((size_t)40 << 20));

  cvt_x_kernel<<<dim3(2048), dim3(256), 0, stream>>>(x, xb);
  wtrans_kernel<<<dim3(16, 16, 4), dim3(256), 0, stream>>>(Wq, Wk, Wv, Wp, wt);
  gemm128_kernel<0><<<dim3(24, 32), dim3(256), 0, stream>>>(
      xb, wt, 1024, qbuf, kbuf, vbuf, bq, bk, bv, (float*)nullptr, (const float*)nullptr);
  fattn_kernel<<<dim3(16, 32), dim3(256), 0, stream>>>(qbuf, kbuf, vbuf, ybuf);
  gemm128_kernel<1><<<dim3(8, 32), dim3(256), 0, stream>>>(
      ybuf, wt + (size_t)3 * 1024 * 1024, 1024,
      (u16*)nullptr, (u16*)nullptr, (u16*)nullptr,
      (const float*)nullptr, (const float*)nullptr, (const float*)nullptr, out, bp);
  (void)in_sizes; (void)n_in; (void)out_size; (void)ws_size;
}

// Round 2
// 178.419 us; speedup vs baseline: 1.2911x; 1.2911x over previous
//
#include <hip/hip_runtime.h>
#include <hip/hip_bf16.h>
#include <stdint.h>

typedef unsigned short u16;
typedef __attribute__((ext_vector_type(8))) short short8;
typedef __attribute__((ext_vector_type(4))) float f32x4;

// ws layout (bytes): [0,8M) x_bf16 (reused as V^T after QKV gemm)
// [8M,16M) Wt(4x1Mx2B) [16M,24M) q [24M,32M) k [32M,40M) v [40M,48M) y
static __device__ __forceinline__ u16 f2bf(float f) {
  unsigned u = __builtin_bit_cast(unsigned, f);
  u += 0x7fffu + ((u >> 16) & 1u);
  return (u16)(u >> 16);
}

static __device__ __forceinline__ void gload16(const u16* g, u16* l) {
  __builtin_amdgcn_global_load_lds(
      (__attribute__((address_space(1))) void*)const_cast<u16*>(g),
      (__attribute__((address_space(3))) void*)l, 16, 0, 0);
}

// ---------------- x fp32 -> bf16 ----------------
__global__ __launch_bounds__(256) void cvt_x_kernel(const float* __restrict__ x,
                                                    u16* __restrict__ xb) {
  size_t i = (size_t)blockIdx.x * 256 + threadIdx.x;  // 8 floats per thread
  const float4* xp = (const float4*)x + i * 2;
  float4 a = xp[0], b = xp[1];
  union { u16 u[8]; int4 v; } r;
  r.u[0] = f2bf(a.x); r.u[1] = f2bf(a.y); r.u[2] = f2bf(a.z); r.u[3] = f2bf(a.w);
  r.u[4] = f2bf(b.x); r.u[5] = f2bf(b.y); r.u[6] = f2bf(b.z); r.u[7] = f2bf(b.w);
  *(int4*)(xb + i * 8) = r.v;
}

// ---------------- W [k][n] fp32 -> Wt [n][k] bf16 (x4 weights) ----------------
__global__ __launch_bounds__(256) void wtrans_kernel(const float* __restrict__ Wq,
                                                     const float* __restrict__ Wk,
                                                     const float* __restrict__ Wv,
                                                     const float* __restrict__ Wp,
                                                     u16* __restrict__ wt) {
  __shared__ float tile[64][65];
  int wz = blockIdx.z;
  const float* W = (wz == 0) ? Wq : (wz == 1) ? Wk : (wz == 2) ? Wv : Wp;
  int n0 = blockIdx.x * 64, k0 = blockIdx.y * 64;
  int tx = threadIdx.x & 63, ty = threadIdx.x >> 6;
#pragma unroll
  for (int r = 0; r < 16; ++r)
    tile[ty + 4 * r][tx] = W[(size_t)(k0 + ty + 4 * r) * 1024 + n0 + tx];
  __syncthreads();
  u16* dst = wt + (size_t)wz * 1024 * 1024;
#pragma unroll
  for (int r = 0; r < 16; ++r) {
    int n = ty + 4 * r;
    dst[(size_t)(n0 + n) * 1024 + k0 + tx] = f2bf(tile[tx][n]);
  }
}

// ---------------- V [B,H,T,D] -> V^T [B,H,D,T], bf16, LDS swizzled ----------------
__global__ __launch_bounds__(256) void vtrans_kernel(const u16* __restrict__ vb,
                                                     u16* __restrict__ vt) {
  __shared__ u16 tile[64 * 64];
  int bh = blockIdx.y, t0 = blockIdx.x * 64;
  size_t base = (size_t)bh * 2048 * 64;
  int tid = threadIdx.x;
#pragma unroll
  for (int it = 0; it < 2; ++it) {
    int chunk = it * 256 + tid;
    int row = chunk >> 3, c8 = (chunk & 7) * 8;  // row = t-rel, c8 = d
    int4 v = *(const int4*)&vb[base + (size_t)(t0 + row) * 64 + c8];
    int addr = (row * 128 + c8 * 2) ^ ((row & 7) << 4);
    *(int4*)((char*)tile + addr) = v;
  }
  __syncthreads();
#pragma unroll
  for (int it = 0; it < 2; ++it) {
    int chunk = it * 256 + tid;
    int d = chunk >> 3, t8 = (chunk & 7) * 8;
    union { u16 u[8]; int4 v; } r;
#pragma unroll
    for (int jj = 0; jj < 8; ++jj) {
      int t = t8 + jj;
      int addr = (t * 128 + d * 2) ^ ((t & 7) << 4);
      r.u[jj] = *(const u16*)((char*)tile + addr);
    }
    *(int4*)&vt[base + (size_t)d * 2048 + t0 + t8] = r.v;
  }
}

// ---------------- 128x128 MFMA GEMM, BK=64, global_load_lds staging ----------------
template <int EPI>
__global__ __launch_bounds__(256) void gemm128_kernel(
    const u16* __restrict__ A, const u16* __restrict__ Bt, int Kdim,
    u16* __restrict__ qd, u16* __restrict__ kd, u16* __restrict__ vd,
    const float* __restrict__ bq, const float* __restrict__ bk,
    const float* __restrict__ bv, float* __restrict__ outf,
    const float* __restrict__ bias1) {
  __shared__ u16 Alds[128 * 64];
  __shared__ u16 Blds[128 * 64];
  int tid = threadIdx.x;
  int lane = tid & 63, w = tid >> 6;
  int l15 = lane & 15, lg = lane >> 4;
  int m0 = blockIdx.y * 128, n0 = blockIdx.x * 128;
  int wm = (w >> 1) * 64, wn = (w & 1) * 64;
  int srow = lane >> 3, scol = (lane & 7) * 8;
  f32x4 acc[4][4] = {};
  for (int kt = 0; kt < Kdim; kt += 64) {
#pragma unroll
    for (int j = 0; j < 4; ++j) {
      int issue = w * 4 + j;
      int row = issue * 8 + srow;
      gload16(&A[(size_t)(m0 + row) * Kdim + kt + scol], &Alds[issue * 512]);
      gload16(&Bt[(size_t)(n0 + row) * Kdim + kt + scol], &Blds[issue * 512]);
    }
    __syncthreads();
#pragma unroll
    for (int kk = 0; kk < 2; ++kk) {
      short8 a[4], b[4];
#pragma unroll
      for (int mt = 0; mt < 4; ++mt)
        a[mt] = *(const short8*)&Alds[(wm + mt * 16 + l15) * 64 + kk * 32 + lg * 8];
#pragma unroll
      for (int nt = 0; nt < 4; ++nt)
        b[nt] = *(const short8*)&Blds[(wn + nt * 16 + l15) * 64 + kk * 32 + lg * 8];
#pragma unroll
      for (int mt = 0; mt < 4; ++mt)
#pragma unroll
        for (int nt = 0; nt < 4; ++nt)
          acc[mt][nt] = __builtin_amdgcn_mfma_f32_16x16x32_bf16(a[mt], b[nt],
                                                                acc[mt][nt], 0, 0, 0);
    }
    __syncthreads();
  }
  if (EPI == 0) {
#pragma unroll
    for (int nt = 0; nt < 4; ++nt) {
      int n = n0 + wn + nt * 16 + l15;
      int wi = n >> 10, nn = n & 1023, h = nn >> 6, d = nn & 63;
      u16* dst = (wi == 0) ? qd : (wi == 1) ? kd : vd;
      const float* bb = (wi == 0) ? bq : (wi == 1) ? bk : bv;
      float bval = bb[nn];
#pragma unroll
      for (int mt = 0; mt < 4; ++mt) {
#pragma unroll
        for (int i = 0; i < 4; ++i) {
          int m = m0 + wm + mt * 16 + lg * 4 + i;
          int mb = m >> 11, t = m & 2047;
          dst[((size_t)(mb * 16 + h) * 2048 + t) * 64 + d] = f2bf(acc[mt][nt][i] + bval);
        }
      }
    }
  } else {
#pragma unroll
    for (int nt = 0; nt < 4; ++nt) {
      int n = n0 + wn + nt * 16 + l15;
      float bval = bias1[n];
#pragma unroll
      for (int mt = 0; mt < 4; ++mt) {
#pragma unroll
        for (int i = 0; i < 4; ++i) {
          int m = m0 + wm + mt * 16 + lg * 4 + i;
          outf[(size_t)m * 1024 + n] = acc[mt][nt][i] + bval;
        }
      }
    }
  }
}

// ---------------- causal flash attention, paired q-tiles for balance ----------------
// Block = pair (qtile pid, qtile 31-pid), each 64 q-rows (4 waves x 16 rows).
// Every block processes exactly 33 KV tiles -> uniform work, 512 blocks.
// K and V^T staged via global_load_lds with pre-swizzled source columns
// (linear LDS dest + XOR'd global col == XOR-swizzled read, m173 pattern).
__global__ __launch_bounds__(256) void fattn_kernel(const u16* __restrict__ qb,
                                                    const u16* __restrict__ kb,
                                                    const u16* __restrict__ vt,
                                                    u16* __restrict__ y) {
  __shared__ u16 Klds[64 * 64];
  __shared__ u16 Vlds[64 * 64];   // V^T: [d][kv], swizzled
  __shared__ u16 Plds[4][16 * 64];
  int tid = threadIdx.x, lane = tid & 63, w = tid >> 6;
  int l15 = lane & 15, lg = lane >> 4;
  int bh = blockIdx.y, pid = blockIdx.x;
  size_t base = (size_t)bh * 2048 * 64;
  int mb = bh >> 4, h = bh & 15;
  const float SC = 0.125f * 1.44269504088896340736f;  // fold /sqrt(64) and log2(e)

  for (int ph = 0; ph < 2; ++ph) {
    int qt = ph ? (31 - pid) : pid;
    int qw = qt * 64 + w * 16;
    short8 qf[2];
#pragma unroll
    for (int kk = 0; kk < 2; ++kk)
      qf[kk] = *(const short8*)&qb[base + (size_t)(qw + l15) * 64 + kk * 32 + lg * 8];
    f32x4 o[4] = {};
    float mrow[4], lrow[4];
#pragma unroll
    for (int i = 0; i < 4; ++i) { mrow[i] = -__builtin_inff(); lrow[i] = 0.f; }
    int ntiles = qt + 1;
    for (int j = 0; j < ntiles; ++j) {
      int k0 = j * 64;
      // stage K [kv][d] and V^T [d][kv], swizzle folded into the global column
#pragma unroll
      for (int it = 0; it < 2; ++it) {
        int chunk = it * 256 + tid;
        int row = chunk >> 3;
        int col = ((chunk & 7) * 8) ^ ((row & 7) << 3);
        int ldsoff = (it * 256 + w * 64) * 8;  // wave-uniform, u16 units
        gload16(&kb[base + (size_t)(k0 + row) * 64 + col], &Klds[ldsoff]);
        gload16(&vt[base + (size_t)row * 2048 + k0 + col], &Vlds[ldsoff]);
      }
      __syncthreads();
      bool diag = (j == qt);
      // S = Q K^T
      f32x4 s[4] = {};
      __builtin_amdgcn_s_setprio(1);
#pragma unroll
      for (int kk = 0; kk < 2; ++kk) {
        short8 bk_[4];
#pragma unroll
        for (int nt = 0; nt < 4; ++nt) {
          int row = nt * 16 + l15;
          int addr = (row * 128 + (kk * 32 + lg * 8) * 2) ^ ((row & 7) << 4);
          bk_[nt] = *(const short8*)((char*)Klds + addr);
        }
#pragma unroll
        for (int nt = 0; nt < 4; ++nt)
          s[nt] = __builtin_amdgcn_mfma_f32_16x16x32_bf16(qf[kk], bk_[nt], s[nt], 0, 0, 0);
      }
      __builtin_amdgcn_s_setprio(0);
      // online softmax (log2 domain, scale pre-folded)
#pragma unroll
      for (int i = 0; i < 4; ++i) {
        int qr = qw + lg * 4 + i;
        float vmax = mrow[i];
        float sv[4];
#pragma unroll
        for (int nt = 0; nt < 4; ++nt) {
          float t = s[nt][i] * SC;
          if (diag && (k0 + nt * 16 + l15 > qr)) t = -__builtin_inff();
          sv[nt] = t;
          vmax = fmaxf(vmax, t);
        }
#pragma unroll
        for (int off = 1; off < 16; off <<= 1)
          vmax = fmaxf(vmax, __shfl_xor(vmax, off));
        float scale = exp2f(mrow[i] - vmax);
        mrow[i] = vmax;
        float rsum = 0.f;
#pragma unroll
        for (int nt = 0; nt < 4; ++nt) {
          float p = exp2f(sv[nt] - vmax);
          rsum += p;
          int row = lg * 4 + i, col = nt * 16 + l15;
          int addr = (row * 128 + col * 2) ^ ((row & 7) << 4);
          *(u16*)((char*)Plds[w] + addr) = f2bf(p);
        }
#pragma unroll
        for (int off = 1; off < 16; off <<= 1)
          rsum += __shfl_xor(rsum, off);
        lrow[i] = lrow[i] * scale + rsum;
#pragma unroll
        for (int dn = 0; dn < 4; ++dn) o[dn][i] *= scale;
      }
      // O += P V
      __builtin_amdgcn_s_setprio(1);
#pragma unroll
      for (int kk = 0; kk < 2; ++kk) {
        int paddr = (l15 * 128 + (kk * 32 + lg * 8) * 2) ^ ((l15 & 7) << 4);
        short8 ap = *(const short8*)((char*)Plds[w] + paddr);
#pragma unroll
        for (int dn = 0; dn < 4; ++dn) {
          int row = dn * 16 + l15;
          int addr = (row * 128 + (kk * 32 + lg * 8) * 2) ^ ((row & 7) << 4);
          short8 bv_ = *(const short8*)((char*)Vlds + addr);
          o[dn] = __builtin_amdgcn_mfma_f32_16x16x32_bf16(ap, bv_, o[dn], 0, 0, 0);
        }
      }
      __builtin_amdgcn_s_setprio(0);
      __syncthreads();
    }
    // normalize + write y [B,T,C] bf16
#pragma unroll
    for (int i = 0; i < 4; ++i) {
      int qr = qw + lg * 4 + i;
      float inv = 1.f / lrow[i];
      size_t rb = ((size_t)(mb * 2048 + qr)) * 1024 + (size_t)h * 64;
#pragma unroll
      for (int dn = 0; dn < 4; ++dn)
        y[rb + dn * 16 + l15] = f2bf(o[dn][i] * inv);
    }
  }
}

extern "C" void kernel_launch(void* const* d_in, const int* in_sizes, int n_in,
                              void* d_out, int out_size, void* d_ws, size_t ws_size,
                              hipStream_t stream) {
  const float* x  = (const float*)d_in[0];
  const float* Wq = (const float*)d_in[1];
  const float* bq = (const float*)d_in[2];
  const float* Wk = (const float*)d_in[3];
  const float* bk = (const float*)d_in[4];
  const float* Wv = (const float*)d_in[5];
  const float* bv = (const float*)d_in[6];
  const float* Wp = (const float*)d_in[7];
  const float* bp = (const float*)d_in[8];
  float* out = (float*)d_out;
  char* ws = (char*)d_ws;
  u16* xb   = (u16*)(ws);
  u16* wt   = (u16*)(ws + ((size_t)8 << 20));
  u16* qbuf = (u16*)(ws + ((size_t)16 << 20));
  u16* kbuf = (u16*)(ws + ((size_t)24 << 20));
  u16* vbuf = (u16*)(ws + ((size_t)32 << 20));
  u16* ybuf = (u16*)(ws + ((size_t)40 << 20));
  u16* vtb  = xb;  // x_bf16 region is dead after the QKV GEMM; reuse for V^T

  cvt_x_kernel<<<dim3(2048), dim3(256), 0, stream>>>(x, xb);
  wtrans_kernel<<<dim3(16, 16, 4), dim3(256), 0, stream>>>(Wq, Wk, Wv, Wp, wt);
  gemm128_kernel<0><<<dim3(24, 32), dim3(256), 0, stream>>>(
      xb, wt, 1024, qbuf, kbuf, vbuf, bq, bk, bv, (float*)nullptr, (const float*)nullptr);
  vtrans_kernel<<<dim3(32, 32), dim3(256), 0, stream>>>(vbuf, vtb);
  fattn_kernel<<<dim3(16, 32), dim3(256), 0, stream>>>(qbuf, kbuf, vtb, ybuf);
  gemm128_kernel<1><<<dim3(8, 32), dim3(256), 0, stream>>>(
      ybuf, wt + (size_t)3 * 1024 * 1024, 1024,
      (u16*)nullptr, (u16*)nullptr, (u16*)nullptr,
      (const float*)nullptr, (const float*)nullptr, (const float*)nullptr, out, bp);
  (void)in_sizes; (void)n_in; (void)out_size; (void)ws_size;
}

// Round 3
// 153.435 us; speedup vs baseline: 1.5013x; 1.1628x over previous
//
#include <hip/hip_runtime.h>
#include <hip/hip_bf16.h>
#include <stdint.h>

typedef unsigned short u16;
typedef __attribute__((ext_vector_type(8))) short short8;
typedef __attribute__((ext_vector_type(4))) float f32x4;

// ws layout (bytes): [0,8M) x_bf16 (reused as V^T after QKV gemm)
// [8M,16M) Wt(4x1Mx2B) [16M,24M) q [24M,32M) k [32M,40M) v [40M,48M) y
static __device__ __forceinline__ u16 f2bf(float f) {
  unsigned u = __builtin_bit_cast(unsigned, f);
  u += 0x7fffu + ((u >> 16) & 1u);
  return (u16)(u >> 16);
}

static __device__ __forceinline__ unsigned cvtpk(float lo, float hi) {
  unsigned r;
  asm("v_cvt_pk_bf16_f32 %0, %1, %2" : "=v"(r) : "v"(lo), "v"(hi));
  return r;
}

static __device__ __forceinline__ void gload16(const u16* g, u16* l) {
  __builtin_amdgcn_global_load_lds(
      (__attribute__((address_space(1))) void*)const_cast<u16*>(g),
      (__attribute__((address_space(3))) void*)l, 16, 0, 0);
}

// ---------------- x fp32 -> bf16 ----------------
__global__ __launch_bounds__(256) void cvt_x_kernel(const float* __restrict__ x,
                                                    u16* __restrict__ xb) {
  size_t i = (size_t)blockIdx.x * 256 + threadIdx.x;  // 8 floats per thread
  const float4* xp = (const float4*)x + i * 2;
  float4 a = xp[0], b = xp[1];
  union { u16 u[8]; int4 v; } r;
  r.u[0] = f2bf(a.x); r.u[1] = f2bf(a.y); r.u[2] = f2bf(a.z); r.u[3] = f2bf(a.w);
  r.u[4] = f2bf(b.x); r.u[5] = f2bf(b.y); r.u[6] = f2bf(b.z); r.u[7] = f2bf(b.w);
  *(int4*)(xb + i * 8) = r.v;
}

// ---------------- W [k][n] fp32 -> Wt [n][k] bf16 (x4 weights) ----------------
__global__ __launch_bounds__(256) void wtrans_kernel(const float* __restrict__ Wq,
                                                     const float* __restrict__ Wk,
                                                     const float* __restrict__ Wv,
                                                     const float* __restrict__ Wp,
                                                     u16* __restrict__ wt) {
  __shared__ float tile[64][65];
  int wz = blockIdx.z;
  const float* W = (wz == 0) ? Wq : (wz == 1) ? Wk : (wz == 2) ? Wv : Wp;
  int n0 = blockIdx.x * 64, k0 = blockIdx.y * 64;
  int tx = threadIdx.x & 63, ty = threadIdx.x >> 6;
#pragma unroll
  for (int r = 0; r < 16; ++r)
    tile[ty + 4 * r][tx] = W[(size_t)(k0 + ty + 4 * r) * 1024 + n0 + tx];
  __syncthreads();
  u16* dst = wt + (size_t)wz * 1024 * 1024;
#pragma unroll
  for (int r = 0; r < 16; ++r) {
    int n = ty + 4 * r;
    dst[(size_t)(n0 + n) * 1024 + k0 + tx] = f2bf(tile[tx][n]);
  }
}

// ---------------- V [B,H,T,D] -> V^T [B,H,D,T], bf16, LDS swizzled ----------------
__global__ __launch_bounds__(256) void vtrans_kernel(const u16* __restrict__ vb,
                                                     u16* __restrict__ vt) {
  __shared__ u16 tile[64 * 64];
  int bh = blockIdx.y, t0 = blockIdx.x * 64;
  size_t base = (size_t)bh * 2048 * 64;
  int tid = threadIdx.x;
#pragma unroll
  for (int it = 0; it < 2; ++it) {
    int chunk = it * 256 + tid;
    int row = chunk >> 3, c8 = (chunk & 7) * 8;  // row = t-rel, c8 = d
    int4 v = *(const int4*)&vb[base + (size_t)(t0 + row) * 64 + c8];
    int addr = (row * 128 + c8 * 2) ^ ((row & 7) << 4);
    *(int4*)((char*)tile + addr) = v;
  }
  __syncthreads();
#pragma unroll
  for (int it = 0; it < 2; ++it) {
    int chunk = it * 256 + tid;
    int d = chunk >> 3, t8 = (chunk & 7) * 8;
    union { u16 u[8]; int4 v; } r;
#pragma unroll
    for (int jj = 0; jj < 8; ++jj) {
      int t = t8 + jj;
      int addr = (t * 128 + d * 2) ^ ((t & 7) << 4);
      r.u[jj] = *(const u16*)((char*)tile + addr);
    }
    *(int4*)&vt[base + (size_t)d * 2048 + t0 + t8] = r.v;
  }
}

// ---------------- 128x128 MFMA GEMM, BK=64, global_load_lds staging ----------------
template <int EPI>
__global__ __launch_bounds__(256) void gemm128_kernel(
    const u16* __restrict__ A, const u16* __restrict__ Bt, int Kdim,
    u16* __restrict__ qd, u16* __restrict__ kd, u16* __restrict__ vd,
    const float* __restrict__ bq, const float* __restrict__ bk,
    const float* __restrict__ bv, float* __restrict__ outf,
    const float* __restrict__ bias1) {
  __shared__ u16 Alds[128 * 64];
  __shared__ u16 Blds[128 * 64];
  int tid = threadIdx.x;
  int lane = tid & 63, w = tid >> 6;
  int l15 = lane & 15, lg = lane >> 4;
  // XCD-aware bijective remap (grid size % 8 == 0): each XCD gets contiguous
  // bx columns -> B-panel L2-resident per XCD.
  int gx = gridDim.x, gy = gridDim.y;
  int flat = blockIdx.y * gx + blockIdx.x;
  int per = (gx * gy) >> 3;
  int f2 = (flat & 7) * per + (flat >> 3);
  int m0 = (f2 % gy) * 128, n0 = (f2 / gy) * 128;
  int wm = (w >> 1) * 64, wn = (w & 1) * 64;
  int srow = lane >> 3, scol = (lane & 7) * 8;
  f32x4 acc[4][4] = {};
  for (int kt = 0; kt < Kdim; kt += 64) {
#pragma unroll
    for (int j = 0; j < 4; ++j) {
      int issue = w * 4 + j;
      int row = issue * 8 + srow;
      gload16(&A[(size_t)(m0 + row) * Kdim + kt + scol], &Alds[issue * 512]);
      gload16(&Bt[(size_t)(n0 + row) * Kdim + kt + scol], &Blds[issue * 512]);
    }
    __syncthreads();
#pragma unroll
    for (int kk = 0; kk < 2; ++kk) {
      short8 a[4], b[4];
#pragma unroll
      for (int mt = 0; mt < 4; ++mt)
        a[mt] = *(const short8*)&Alds[(wm + mt * 16 + l15) * 64 + kk * 32 + lg * 8];
#pragma unroll
      for (int nt = 0; nt < 4; ++nt)
        b[nt] = *(const short8*)&Blds[(wn + nt * 16 + l15) * 64 + kk * 32 + lg * 8];
#pragma unroll
      for (int mt = 0; mt < 4; ++mt)
#pragma unroll
        for (int nt = 0; nt < 4; ++nt)
          acc[mt][nt] = __builtin_amdgcn_mfma_f32_16x16x32_bf16(a[mt], b[nt],
                                                                acc[mt][nt], 0, 0, 0);
    }
    __syncthreads();
  }
  if (EPI == 0) {
#pragma unroll
    for (int nt = 0; nt < 4; ++nt) {
      int n = n0 + wn + nt * 16 + l15;
      int wi = n >> 10, nn = n & 1023, h = nn >> 6, d = nn & 63;
      u16* dst = (wi == 0) ? qd : (wi == 1) ? kd : vd;
      const float* bb = (wi == 0) ? bq : (wi == 1) ? bk : bv;
      float bval = bb[nn];
#pragma unroll
      for (int mt = 0; mt < 4; ++mt) {
#pragma unroll
        for (int i = 0; i < 4; ++i) {
          int m = m0 + wm + mt * 16 + lg * 4 + i;
          int mb = m >> 11, t = m & 2047;
          dst[((size_t)(mb * 16 + h) * 2048 + t) * 64 + d] = f2bf(acc[mt][nt][i] + bval);
        }
      }
    }
  } else {
#pragma unroll
    for (int nt = 0; nt < 4; ++nt) {
      int n = n0 + wn + nt * 16 + l15;
      float bval = bias1[n];
#pragma unroll
      for (int mt = 0; mt < 4; ++mt) {
#pragma unroll
        for (int i = 0; i < 4; ++i) {
          int m = m0 + wm + mt * 16 + lg * 4 + i;
          outf[(size_t)m * 1024 + n] = acc[mt][nt][i] + bval;
        }
      }
    }
  }
}

// ---------------- causal flash attention, swapped-operand MFMA ----------------
// S^T = mfma(K_frag, Q_frag): lane holds 16 S values of q-row (lane&15) ->
// in-lane softmax (trees + 2 shuffles). O^T = mfma(Vt_frag, P_frag): O cols
// = q = lane&15, so rescale is lane-local. Paired q-tiles (33 KV tiles per
// block), XCD remap (4 heads per XCD, K+Vt = 2MB L2-resident), double-
// buffered global_load_lds staging with one barrier per tile.
__global__ __launch_bounds__(256) void fattn_kernel(const u16* __restrict__ qb,
                                                    const u16* __restrict__ kb,
                                                    const u16* __restrict__ vt,
                                                    u16* __restrict__ y) {
  __shared__ u16 Klds[2][64 * 64];
  __shared__ u16 Vlds[2][64 * 64];   // V^T: [d][kv], swizzled
  __shared__ u16 Plds[4][16 * 64];
  int tid = threadIdx.x, lane = tid & 63, w = tid >> 6;
  int l15 = lane & 15, lg = lane >> 4;
  // XCD remap: blocks flat%8==c -> heads {c, c+8, c+16, c+24}
  int flat = blockIdx.y * 16 + blockIdx.x;
  int bh = (flat & 7) + (((flat >> 3) & 3) << 3);
  int pid = flat >> 5;
  size_t base = (size_t)bh * 2048 * 64;
  int mb = bh >> 4, h = bh & 15;
  const float SC = 0.125f * 1.44269504088896340736f;  // fold /sqrt(64), log2(e)
  const float NINF = -__builtin_inff();
  int cb = 0;

  for (int ph = 0; ph < 2; ++ph) {
    int qt = ph ? (31 - pid) : pid;
    int qw = qt * 64 + w * 16;
    int qr = qw + l15;
    short8 qf[2];
#pragma unroll
    for (int kk = 0; kk < 2; ++kk)
      qf[kk] = *(const short8*)&qb[base + (size_t)qr * 64 + kk * 32 + lg * 8];
    f32x4 o[4] = {};
    float mrow = NINF, lrow = 0.f;
    __syncthreads();  // LDS reuse across phases
    {  // prologue stage tile 0 into cb
      int k0 = 0;
#pragma unroll
      for (int it = 0; it < 2; ++it) {
        int chunk = it * 256 + tid;
        int row = chunk >> 3;
        int col = ((chunk & 7) * 8) ^ ((row & 7) << 3);
        int ldsoff = (it * 256 + w * 64) * 8;
        gload16(&kb[base + (size_t)(k0 + row) * 64 + col], &Klds[cb][ldsoff]);
        gload16(&vt[base + (size_t)row * 2048 + k0 + col], &Vlds[cb][ldsoff]);
      }
    }
    int ntiles = qt + 1;
    for (int j = 0; j < ntiles; ++j) {
      __syncthreads();  // compiler drains vmcnt before barrier: buf[cb] ready
      if (j + 1 < ntiles) {  // prefetch next tile into cb^1
        int k0 = (j + 1) * 64;
        int nb = cb ^ 1;
#pragma unroll
        for (int it = 0; it < 2; ++it) {
          int chunk = it * 256 + tid;
          int row = chunk >> 3;
          int col = ((chunk & 7) * 8) ^ ((row & 7) << 3);
          int ldsoff = (it * 256 + w * 64) * 8;
          gload16(&kb[base + (size_t)(k0 + row) * 64 + col], &Klds[nb][ldsoff]);
          gload16(&vt[base + (size_t)row * 2048 + k0 + col], &Vlds[nb][ldsoff]);
        }
      }
      // S^T = K Q^T  (swapped operands)
      f32x4 s[4] = {};
      __builtin_amdgcn_s_setprio(1);
#pragma unroll
      for (int kk = 0; kk < 2; ++kk) {
        short8 ka[4];
#pragma unroll
        for (int nt = 0; nt < 4; ++nt) {
          int row = nt * 16 + l15;
          int addr = (row * 128 + kk * 64 + lg * 16) ^ ((row & 7) << 4);
          ka[nt] = *(const short8*)((char*)Klds[cb] + addr);
        }
#pragma unroll
        for (int nt = 0; nt < 4; ++nt)
          s[nt] = __builtin_amdgcn_mfma_f32_16x16x32_bf16(ka[nt], qf[kk], s[nt], 0, 0, 0);
      }
      __builtin_amdgcn_s_setprio(0);
      // in-lane online softmax for q-row qr (lane-local over 16 k values)
      float sv[16];
      if (j == qt) {
#pragma unroll
        for (int nt = 0; nt < 4; ++nt)
#pragma unroll
          for (int i = 0; i < 4; ++i) {
            int ka_ = j * 64 + nt * 16 + lg * 4 + i;
            sv[nt * 4 + i] = (ka_ > qr) ? NINF : s[nt][i] * SC;
          }
      } else {
#pragma unroll
        for (int nt = 0; nt < 4; ++nt)
#pragma unroll
          for (int i = 0; i < 4; ++i) sv[nt * 4 + i] = s[nt][i] * SC;
      }
      float m0_ = fmaxf(fmaxf(fmaxf(sv[0], sv[1]), fmaxf(sv[2], sv[3])),
                        fmaxf(fmaxf(sv[4], sv[5]), fmaxf(sv[6], sv[7])));
      float m1_ = fmaxf(fmaxf(fmaxf(sv[8], sv[9]), fmaxf(sv[10], sv[11])),
                        fmaxf(fmaxf(sv[12], sv[13]), fmaxf(sv[14], sv[15])));
      float vmax = fmaxf(fmaxf(m0_, m1_), mrow);
      vmax = fmaxf(vmax, __shfl_xor(vmax, 16));
      vmax = fmaxf(vmax, __shfl_xor(vmax, 32));
      float scale = exp2f(mrow - vmax);
      mrow = vmax;
#pragma unroll
      for (int u = 0; u < 16; ++u) sv[u] = exp2f(sv[u] - vmax);
      float r0 = ((sv[0] + sv[1]) + (sv[2] + sv[3])) + ((sv[4] + sv[5]) + (sv[6] + sv[7]));
      float r1 = ((sv[8] + sv[9]) + (sv[10] + sv[11])) + ((sv[12] + sv[13]) + (sv[14] + sv[15]));
      float rsum = r0 + r1;
      rsum += __shfl_xor(rsum, 16);
      rsum += __shfl_xor(rsum, 32);
      lrow = lrow * scale + rsum;
#pragma unroll
      for (int dn = 0; dn < 4; ++dn) o[dn] *= scale;
      // P[q][k] -> LDS, packed b64 (4 consecutive k per write)
#pragma unroll
      for (int nt = 0; nt < 4; ++nt) {
        unsigned plo = cvtpk(sv[nt * 4 + 0], sv[nt * 4 + 1]);
        unsigned phi = cvtpk(sv[nt * 4 + 2], sv[nt * 4 + 3]);
        int addr = (l15 * 128 + nt * 32 + lg * 8) ^ ((l15 & 7) << 4);
        *(uint2*)((char*)Plds[w] + addr) = make_uint2(plo, phi);
      }
      // O^T += V^T P^T  (swapped operands)
      __builtin_amdgcn_s_setprio(1);
#pragma unroll
      for (int kk = 0; kk < 2; ++kk) {
        int paddr = (l15 * 128 + kk * 64 + lg * 16) ^ ((l15 & 7) << 4);
        short8 ap = *(const short8*)((char*)Plds[w] + paddr);
#pragma unroll
        for (int dn = 0; dn < 4; ++dn) {
          int row = dn * 16 + l15;
          int addr = (row * 128 + kk * 64 + lg * 16) ^ ((row & 7) << 4);
          short8 bv_ = *(const short8*)((char*)Vlds[cb] + addr);
          o[dn] = __builtin_amdgcn_mfma_f32_16x16x32_bf16(bv_, ap, o[dn], 0, 0, 0);
        }
      }
      __builtin_amdgcn_s_setprio(0);
      cb ^= 1;
    }
    // normalize + write y [B,T,C] bf16; O^T frag: d = dn*16+lg*4+i, q = qr
    float inv = 1.f / lrow;
    size_t rb = ((size_t)(mb * 2048 + qr)) * 1024 + (size_t)h * 64;
#pragma unroll
    for (int dn = 0; dn < 4; ++dn) {
      unsigned lo = cvtpk(o[dn][0] * inv, o[dn][1] * inv);
      unsigned hi = cvtpk(o[dn][2] * inv, o[dn][3] * inv);
      *(uint2*)&y[rb + dn * 16 + lg * 4] = make_uint2(lo, hi);
    }
  }
}

extern "C" void kernel_launch(void* const* d_in, const int* in_sizes, int n_in,
                              void* d_out, int out_size, void* d_ws, size_t ws_size,
                              hipStream_t stream) {
  const float* x  = (const float*)d_in[0];
  const float* Wq = (const float*)d_in[1];
  const float* bq = (const float*)d_in[2];
  const float* Wk = (const float*)d_in[3];
  const float* bk = (const float*)d_in[4];
  const float* Wv = (const float*)d_in[5];
  const float* bv = (const float*)d_in[6];
  const float* Wp = (const float*)d_in[7];
  const float* bp = (const float*)d_in[8];
  float* out = (float*)d_out;
  char* ws = (char*)d_ws;
  u16* xb   = (u16*)(ws);
  u16* wt   = (u16*)(ws + ((size_t)8 << 20));
  u16* qbuf = (u16*)(ws + ((size_t)16 << 20));
  u16* kbuf = (u16*)(ws + ((size_t)24 << 20));
  u16* vbuf = (u16*)(ws + ((size_t)32 << 20));
  u16* ybuf = (u16*)(ws + ((size_t)40 << 20));
  u16* vtb  = xb;  // x_bf16 region is dead after the QKV GEMM; reuse for V^T

  cvt_x_kernel<<<dim3(2048), dim3(256), 0, stream>>>(x, xb);
  wtrans_kernel<<<dim3(16, 16, 4), dim3(256), 0, stream>>>(Wq, Wk, Wv, Wp, wt);
  gemm128_kernel<0><<<dim3(24, 32), dim3(256), 0, stream>>>(
      xb, wt, 1024, qbuf, kbuf, vbuf, bq, bk, bv, (float*)nullptr, (const float*)nullptr);
  vtrans_kernel<<<dim3(32, 32), dim3(256), 0, stream>>>(vbuf, vtb);
  fattn_kernel<<<dim3(16, 32), dim3(256), 0, stream>>>(qbuf, kbuf, vtb, ybuf);
  gemm128_kernel<1><<<dim3(8, 32), dim3(256), 0, stream>>>(
      ybuf, wt + (size_t)3 * 1024 * 1024, 1024,
      (u16*)nullptr, (u16*)nullptr, (u16*)nullptr,
      (const float*)nullptr, (const float*)nullptr, (const float*)nullptr, out, bp);
  (void)in_sizes; (void)n_in; (void)out_size; (void)ws_size;
}

// Round 4
// 147.650 us; speedup vs baseline: 1.5601x; 1.0392x over previous
//
#include <hip/hip_runtime.h>
#include <hip/hip_bf16.h>
#include <stdint.h>

typedef unsigned short u16;
typedef __attribute__((ext_vector_type(8))) short short8;
typedef __attribute__((ext_vector_type(4))) float f32x4;

// ws layout (bytes): [0,8M) x_bf16 (reused as V^T after QKV gemm)
// [8M,16M) Wt(4x1Mx2B) [16M,24M) q [24M,32M) k [32M,40M) v [40M,48M) y
static __device__ __forceinline__ u16 f2bf(float f) {
  unsigned u = __builtin_bit_cast(unsigned, f);
  u += 0x7fffu + ((u >> 16) & 1u);
  return (u16)(u >> 16);
}

static __device__ __forceinline__ unsigned cvtpk(float lo, float hi) {
  unsigned r;
  asm("v_cvt_pk_bf16_f32 %0, %1, %2" : "=v"(r) : "v"(lo), "v"(hi));
  return r;
}

static __device__ __forceinline__ void gload16(const u16* g, u16* l) {
  __builtin_amdgcn_global_load_lds(
      (__attribute__((address_space(1))) void*)const_cast<u16*>(g),
      (__attribute__((address_space(3))) void*)l, 16, 0, 0);
}

// ---------------- x fp32 -> bf16 ----------------
__global__ __launch_bounds__(256) void cvt_x_kernel(const float* __restrict__ x,
                                                    u16* __restrict__ xb) {
  size_t i = (size_t)blockIdx.x * 256 + threadIdx.x;  // 8 floats per thread
  const float4* xp = (const float4*)x + i * 2;
  float4 a = xp[0], b = xp[1];
  union { u16 u[8]; int4 v; } r;
  r.u[0] = f2bf(a.x); r.u[1] = f2bf(a.y); r.u[2] = f2bf(a.z); r.u[3] = f2bf(a.w);
  r.u[4] = f2bf(b.x); r.u[5] = f2bf(b.y); r.u[6] = f2bf(b.z); r.u[7] = f2bf(b.w);
  *(int4*)(xb + i * 8) = r.v;
}

// ---------------- W [k][n] fp32 -> Wt [n][k] bf16 (x4 weights) ----------------
__global__ __launch_bounds__(256) void wtrans_kernel(const float* __restrict__ Wq,
                                                     const float* __restrict__ Wk,
                                                     const float* __restrict__ Wv,
                                                     const float* __restrict__ Wp,
                                                     u16* __restrict__ wt) {
  __shared__ float tile[64][65];
  int wz = blockIdx.z;
  const float* W = (wz == 0) ? Wq : (wz == 1) ? Wk : (wz == 2) ? Wv : Wp;
  int n0 = blockIdx.x * 64, k0 = blockIdx.y * 64;
  int tx = threadIdx.x & 63, ty = threadIdx.x >> 6;
#pragma unroll
  for (int r = 0; r < 16; ++r)
    tile[ty + 4 * r][tx] = W[(size_t)(k0 + ty + 4 * r) * 1024 + n0 + tx];
  __syncthreads();
  u16* dst = wt + (size_t)wz * 1024 * 1024;
#pragma unroll
  for (int r = 0; r < 16; ++r) {
    int n = ty + 4 * r;
    dst[(size_t)(n0 + n) * 1024 + k0 + tx] = f2bf(tile[tx][n]);
  }
}

// ---------------- V [B,H,T,D] -> V^T [B,H,D,T], bf16, LDS swizzled ----------------
__global__ __launch_bounds__(256) void vtrans_kernel(const u16* __restrict__ vb,
                                                     u16* __restrict__ vt) {
  __shared__ u16 tile[64 * 64];
  int bh = blockIdx.y, t0 = blockIdx.x * 64;
  size_t base = (size_t)bh * 2048 * 64;
  int tid = threadIdx.x;
#pragma unroll
  for (int it = 0; it < 2; ++it) {
    int chunk = it * 256 + tid;
    int row = chunk >> 3, c8 = (chunk & 7) * 8;  // row = t-rel, c8 = d
    int4 v = *(const int4*)&vb[base + (size_t)(t0 + row) * 64 + c8];
    int addr = (row * 128 + c8 * 2) ^ ((row & 7) << 4);
    *(int4*)((char*)tile + addr) = v;
  }
  __syncthreads();
#pragma unroll
  for (int it = 0; it < 2; ++it) {
    int chunk = it * 256 + tid;
    int d = chunk >> 3, t8 = (chunk & 7) * 8;
    union { u16 u[8]; int4 v; } r;
#pragma unroll
    for (int jj = 0; jj < 8; ++jj) {
      int t = t8 + jj;
      int addr = (t * 128 + d * 2) ^ ((t & 7) << 4);
      r.u[jj] = *(const u16*)((char*)tile + addr);
    }
    *(int4*)&vt[base + (size_t)d * 2048 + t0 + t8] = r.v;
  }
}

// ---------------- 128x128 MFMA GEMM, BK=64, global_load_lds staging ----------------
template <int EPI>
__global__ __launch_bounds__(256) void gemm128_kernel(
    const u16* __restrict__ A, const u16* __restrict__ Bt, int Kdim,
    u16* __restrict__ qd, u16* __restrict__ kd, u16* __restrict__ vd,
    const float* __restrict__ bq, const float* __restrict__ bk,
    const float* __restrict__ bv, float* __restrict__ outf,
    const float* __restrict__ bias1) {
  __shared__ u16 Alds[128 * 64];
  __shared__ u16 Blds[128 * 64];
  int tid = threadIdx.x;
  int lane = tid & 63, w = tid >> 6;
  int l15 = lane & 15, lg = lane >> 4;
  // XCD-aware bijective remap (grid size % 8 == 0)
  int gx = gridDim.x, gy = gridDim.y;
  int flat = blockIdx.y * gx + blockIdx.x;
  int per = (gx * gy) >> 3;
  int f2 = (flat & 7) * per + (flat >> 3);
  int m0 = (f2 % gy) * 128, n0 = (f2 / gy) * 128;
  int wm = (w >> 1) * 64, wn = (w & 1) * 64;
  int srow = lane >> 3, scol = (lane & 7) * 8;
  f32x4 acc[4][4] = {};
  for (int kt = 0; kt < Kdim; kt += 64) {
#pragma unroll
    for (int j = 0; j < 4; ++j) {
      int issue = w * 4 + j;
      int row = issue * 8 + srow;
      gload16(&A[(size_t)(m0 + row) * Kdim + kt + scol], &Alds[issue * 512]);
      gload16(&Bt[(size_t)(n0 + row) * Kdim + kt + scol], &Blds[issue * 512]);
    }
    __syncthreads();
#pragma unroll
    for (int kk = 0; kk < 2; ++kk) {
      short8 a[4], b[4];
#pragma unroll
      for (int mt = 0; mt < 4; ++mt)
        a[mt] = *(const short8*)&Alds[(wm + mt * 16 + l15) * 64 + kk * 32 + lg * 8];
#pragma unroll
      for (int nt = 0; nt < 4; ++nt)
        b[nt] = *(const short8*)&Blds[(wn + nt * 16 + l15) * 64 + kk * 32 + lg * 8];
#pragma unroll
      for (int mt = 0; mt < 4; ++mt)
#pragma unroll
        for (int nt = 0; nt < 4; ++nt)
          acc[mt][nt] = __builtin_amdgcn_mfma_f32_16x16x32_bf16(a[mt], b[nt],
                                                                acc[mt][nt], 0, 0, 0);
    }
    __syncthreads();
  }
  if (EPI == 0) {
#pragma unroll
    for (int nt = 0; nt < 4; ++nt) {
      int n = n0 + wn + nt * 16 + l15;
      int wi = n >> 10, nn = n & 1023, h = nn >> 6, d = nn & 63;
      u16* dst = (wi == 0) ? qd : (wi == 1) ? kd : vd;
      const float* bb = (wi == 0) ? bq : (wi == 1) ? bk : bv;
      float bval = bb[nn];
#pragma unroll
      for (int mt = 0; mt < 4; ++mt) {
#pragma unroll
        for (int i = 0; i < 4; ++i) {
          int m = m0 + wm + mt * 16 + lg * 4 + i;
          int mb = m >> 11, t = m & 2047;
          dst[((size_t)(mb * 16 + h) * 2048 + t) * 64 + d] = f2bf(acc[mt][nt][i] + bval);
        }
      }
    }
  } else {
#pragma unroll
    for (int nt = 0; nt < 4; ++nt) {
      int n = n0 + wn + nt * 16 + l15;
      float bval = bias1[n];
#pragma unroll
      for (int mt = 0; mt < 4; ++mt) {
#pragma unroll
        for (int i = 0; i < 4; ++i) {
          int m = m0 + wm + mt * 16 + lg * 4 + i;
          outf[(size_t)m * 1024 + n] = acc[mt][nt][i] + bval;
        }
      }
    }
  }
}

// ---------------- causal flash attention, swapped-operand MFMA ----------------
// 1024 blocks: one 64-row q-tile each (4 waves x 16 rows), longest-first
// (qt = 31 - flat>>5) so the 32-tile blocks launch first -> good makespan at
// 4 blocks/CU (LDS 40KB). head = flat&31 keeps flat%8 == head%8 -> each XCD
// serves 4 heads, K+V^T L2-resident. Double-buffered global_load_lds staging,
// one barrier per tile. T13 defer-max (THR=8) skips O-rescale on most tiles.
__global__ __launch_bounds__(256) void fattn_kernel(const u16* __restrict__ qb,
                                                    const u16* __restrict__ kb,
                                                    const u16* __restrict__ vt,
                                                    u16* __restrict__ y) {
  __shared__ u16 Klds[2][64 * 64];
  __shared__ u16 Vlds[2][64 * 64];   // V^T: [d][kv], swizzled
  __shared__ u16 Plds[4][16 * 64];
  int tid = threadIdx.x, lane = tid & 63, w = tid >> 6;
  int l15 = lane & 15, lg = lane >> 4;
  int flat = blockIdx.x;
  int bh = flat & 31;
  int qt = 31 - (flat >> 5);          // longest-first dispatch
  size_t base = (size_t)bh * 2048 * 64;
  int mb = bh >> 4, h = bh & 15;
  const float SC = 0.125f * 1.44269504088896340736f;  // fold /sqrt(64), log2(e)
  const float NINF = -__builtin_inff();
  int cb = 0;

  int qw = qt * 64 + w * 16;
  int qr = qw + l15;
  short8 qf[2];
#pragma unroll
  for (int kk = 0; kk < 2; ++kk)
    qf[kk] = *(const short8*)&qb[base + (size_t)qr * 64 + kk * 32 + lg * 8];
  f32x4 o[4] = {};
  float mrow = NINF, lrow = 0.f;
  {  // prologue stage tile 0 into cb
#pragma unroll
    for (int it = 0; it < 2; ++it) {
      int chunk = it * 256 + tid;
      int row = chunk >> 3;
      int col = ((chunk & 7) * 8) ^ ((row & 7) << 3);
      int ldsoff = (it * 256 + w * 64) * 8;
      gload16(&kb[base + (size_t)row * 64 + col], &Klds[cb][ldsoff]);
      gload16(&vt[base + (size_t)row * 2048 + col], &Vlds[cb][ldsoff]);
    }
  }
  int ntiles = qt + 1;
  for (int j = 0; j < ntiles; ++j) {
    __syncthreads();  // compiler drains vmcnt before barrier: buf[cb] ready
    if (j + 1 < ntiles) {  // prefetch next tile into cb^1
      int k0 = (j + 1) * 64;
      int nb = cb ^ 1;
#pragma unroll
      for (int it = 0; it < 2; ++it) {
        int chunk = it * 256 + tid;
        int row = chunk >> 3;
        int col = ((chunk & 7) * 8) ^ ((row & 7) << 3);
        int ldsoff = (it * 256 + w * 64) * 8;
        gload16(&kb[base + (size_t)(k0 + row) * 64 + col], &Klds[nb][ldsoff]);
        gload16(&vt[base + (size_t)row * 2048 + k0 + col], &Vlds[nb][ldsoff]);
      }
    }
    // S^T = K Q^T  (swapped operands)
    f32x4 s[4] = {};
    __builtin_amdgcn_s_setprio(1);
#pragma unroll
    for (int kk = 0; kk < 2; ++kk) {
      short8 ka[4];
#pragma unroll
      for (int nt = 0; nt < 4; ++nt) {
        int row = nt * 16 + l15;
        int addr = (row * 128 + kk * 64 + lg * 16) ^ ((row & 7) << 4);
        ka[nt] = *(const short8*)((char*)Klds[cb] + addr);
      }
#pragma unroll
      for (int nt = 0; nt < 4; ++nt)
        s[nt] = __builtin_amdgcn_mfma_f32_16x16x32_bf16(ka[nt], qf[kk], s[nt], 0, 0, 0);
    }
    __builtin_amdgcn_s_setprio(0);
    // in-lane online softmax for q-row qr (lane-local over 16 k values)
    float sv[16];
    if (j == qt) {
#pragma unroll
      for (int nt = 0; nt < 4; ++nt)
#pragma unroll
        for (int i = 0; i < 4; ++i) {
          int ka_ = j * 64 + nt * 16 + lg * 4 + i;
          sv[nt * 4 + i] = (ka_ > qr) ? NINF : s[nt][i] * SC;
        }
    } else {
#pragma unroll
      for (int nt = 0; nt < 4; ++nt)
#pragma unroll
        for (int i = 0; i < 4; ++i) sv[nt * 4 + i] = s[nt][i] * SC;
    }
    float m0_ = fmaxf(fmaxf(fmaxf(sv[0], sv[1]), fmaxf(sv[2], sv[3])),
                      fmaxf(fmaxf(sv[4], sv[5]), fmaxf(sv[6], sv[7])));
    float m1_ = fmaxf(fmaxf(fmaxf(sv[8], sv[9]), fmaxf(sv[10], sv[11])),
                      fmaxf(fmaxf(sv[12], sv[13]), fmaxf(sv[14], sv[15])));
    float tmax = fmaxf(m0_, m1_);
    tmax = fmaxf(tmax, __shfl_xor(tmax, 16));
    tmax = fmaxf(tmax, __shfl_xor(tmax, 32));
    // T13 defer-max: only rescale when the tile max overshoots the running
    // max by >8 (P then bounded by 2^8 -- fine in bf16/f32).
    if (!__all(tmax <= mrow + 8.f)) {
      float vmax = fmaxf(tmax, mrow);
      float scale = exp2f(mrow - vmax);
      mrow = vmax;
      lrow *= scale;
#pragma unroll
      for (int dn = 0; dn < 4; ++dn) o[dn] *= scale;
    }
#pragma unroll
    for (int u = 0; u < 16; ++u) sv[u] = exp2f(sv[u] - mrow);
    float r0 = ((sv[0] + sv[1]) + (sv[2] + sv[3])) + ((sv[4] + sv[5]) + (sv[6] + sv[7]));
    float r1 = ((sv[8] + sv[9]) + (sv[10] + sv[11])) + ((sv[12] + sv[13]) + (sv[14] + sv[15]));
    float rsum = r0 + r1;
    rsum += __shfl_xor(rsum, 16);
    rsum += __shfl_xor(rsum, 32);
    lrow += rsum;
    // P[q][k] -> LDS, packed b64 (4 consecutive k per write)
#pragma unroll
    for (int nt = 0; nt < 4; ++nt) {
      unsigned plo = cvtpk(sv[nt * 4 + 0], sv[nt * 4 + 1]);
      unsigned phi = cvtpk(sv[nt * 4 + 2], sv[nt * 4 + 3]);
      int addr = (l15 * 128 + nt * 32 + lg * 8) ^ ((l15 & 7) << 4);
      *(uint2*)((char*)Plds[w] + addr) = make_uint2(plo, phi);
    }
    // O^T += V^T P^T  (swapped operands)
    __builtin_amdgcn_s_setprio(1);
#pragma unroll
    for (int kk = 0; kk < 2; ++kk) {
      int paddr = (l15 * 128 + kk * 64 + lg * 16) ^ ((l15 & 7) << 4);
      short8 ap = *(const short8*)((char*)Plds[w] + paddr);
#pragma unroll
      for (int dn = 0; dn < 4; ++dn) {
        int row = dn * 16 + l15;
        int addr = (row * 128 + kk * 64 + lg * 16) ^ ((row & 7) << 4);
        short8 bv_ = *(const short8*)((char*)Vlds[cb] + addr);
        o[dn] = __builtin_amdgcn_mfma_f32_16x16x32_bf16(bv_, ap, o[dn], 0, 0, 0);
      }
    }
    __builtin_amdgcn_s_setprio(0);
    cb ^= 1;
  }
  // normalize + write y [B,T,C] bf16; O^T frag: d = dn*16+lg*4+i, q = qr
  float inv = 1.f / lrow;
  size_t rb = ((size_t)(mb * 2048 + qr)) * 1024 + (size_t)h * 64;
#pragma unroll
  for (int dn = 0; dn < 4; ++dn) {
    unsigned lo = cvtpk(o[dn][0] * inv, o[dn][1] * inv);
    unsigned hi = cvtpk(o[dn][2] * inv, o[dn][3] * inv);
    *(uint2*)&y[rb + dn * 16 + lg * 4] = make_uint2(lo, hi);
  }
}

extern "C" void kernel_launch(void* const* d_in, const int* in_sizes, int n_in,
                              void* d_out, int out_size, void* d_ws, size_t ws_size,
                              hipStream_t stream) {
  const float* x  = (const float*)d_in[0];
  const float* Wq = (const float*)d_in[1];
  const float* bq = (const float*)d_in[2];
  const float* Wk = (const float*)d_in[3];
  const float* bk = (const float*)d_in[4];
  const float* Wv = (const float*)d_in[5];
  const float* bv = (const float*)d_in[6];
  const float* Wp = (const float*)d_in[7];
  const float* bp = (const float*)d_in[8];
  float* out = (float*)d_out;
  char* ws = (char*)d_ws;
  u16* xb   = (u16*)(ws);
  u16* wt   = (u16*)(ws + ((size_t)8 << 20));
  u16* qbuf = (u16*)(ws + ((size_t)16 << 20));
  u16* kbuf = (u16*)(ws + ((size_t)24 << 20));
  u16* vbuf = (u16*)(ws + ((size_t)32 << 20));
  u16* ybuf = (u16*)(ws + ((size_t)40 << 20));
  u16* vtb  = xb;  // x_bf16 region is dead after the QKV GEMM; reuse for V^T

  cvt_x_kernel<<<dim3(2048), dim3(256), 0, stream>>>(x, xb);
  wtrans_kernel<<<dim3(16, 16, 4), dim3(256), 0, stream>>>(Wq, Wk, Wv, Wp, wt);
  gemm128_kernel<0><<<dim3(24, 32), dim3(256), 0, stream>>>(
      xb, wt, 1024, qbuf, kbuf, vbuf, bq, bk, bv, (float*)nullptr, (const float*)nullptr);
  vtrans_kernel<<<dim3(32, 32), dim3(256), 0, stream>>>(vbuf, vtb);
  fattn_kernel<<<dim3(1024), dim3(256), 0, stream>>>(qbuf, kbuf, vtb, ybuf);
  gemm128_kernel<1><<<dim3(8, 32), dim3(256), 0, stream>>>(
      ybuf, wt + (size_t)3 * 1024 * 1024, 1024,
      (u16*)nullptr, (u16*)nullptr, (u16*)nullptr,
      (const float*)nullptr, (const float*)nullptr, (const float*)nullptr, out, bp);
  (void)in_sizes; (void)n_in; (void)out_size; (void)ws_size;
}

// Round 5
// 129.863 us; speedup vs baseline: 1.7738x; 1.1370x over previous
//
#include <hip/hip_runtime.h>
#include <hip/hip_bf16.h>
#include <stdint.h>

typedef unsigned short u16;
typedef __attribute__((ext_vector_type(8))) short short8;
typedef __attribute__((ext_vector_type(4))) float f32x4;

// ws layout (bytes): [0,8M) x_bf16 (reused as V^T after QKV gemm)
// [8M,16M) Wt(4x1Mx2B) [16M,24M) q [24M,32M) k [32M,40M) v [40M,48M) y
static __device__ __forceinline__ u16 f2bf(float f) {
  unsigned u = __builtin_bit_cast(unsigned, f);
  u += 0x7fffu + ((u >> 16) & 1u);
  return (u16)(u >> 16);
}

static __device__ __forceinline__ unsigned cvtpk(float lo, float hi) {
  unsigned r;
  asm("v_cvt_pk_bf16_f32 %0, %1, %2" : "=v"(r) : "v"(lo), "v"(hi));
  return r;
}

static __device__ __forceinline__ void gload16(const u16* g, u16* l) {
  __builtin_amdgcn_global_load_lds(
      (__attribute__((address_space(1))) void*)const_cast<u16*>(g),
      (__attribute__((address_space(3))) void*)l, 16, 0, 0);
}

// ---------------- x fp32 -> bf16 ----------------
__global__ __launch_bounds__(256) void cvt_x_kernel(const float* __restrict__ x,
                                                    u16* __restrict__ xb) {
  size_t i = (size_t)blockIdx.x * 256 + threadIdx.x;  // 8 floats per thread
  const float4* xp = (const float4*)x + i * 2;
  float4 a = xp[0], b = xp[1];
  union { u16 u[8]; int4 v; } r;
  r.u[0] = f2bf(a.x); r.u[1] = f2bf(a.y); r.u[2] = f2bf(a.z); r.u[3] = f2bf(a.w);
  r.u[4] = f2bf(b.x); r.u[5] = f2bf(b.y); r.u[6] = f2bf(b.z); r.u[7] = f2bf(b.w);
  *(int4*)(xb + i * 8) = r.v;
}

// ---------------- W [k][n] fp32 -> Wt [n][k] bf16 (x4 weights) ----------------
__global__ __launch_bounds__(256) void wtrans_kernel(const float* __restrict__ Wq,
                                                     const float* __restrict__ Wk,
                                                     const float* __restrict__ Wv,
                                                     const float* __restrict__ Wp,
                                                     u16* __restrict__ wt) {
  __shared__ float tile[64][65];
  int wz = blockIdx.z;
  const float* W = (wz == 0) ? Wq : (wz == 1) ? Wk : (wz == 2) ? Wv : Wp;
  int n0 = blockIdx.x * 64, k0 = blockIdx.y * 64;
  int tx = threadIdx.x & 63, ty = threadIdx.x >> 6;
#pragma unroll
  for (int r = 0; r < 16; ++r)
    tile[ty + 4 * r][tx] = W[(size_t)(k0 + ty + 4 * r) * 1024 + n0 + tx];
  __syncthreads();
  u16* dst = wt + (size_t)wz * 1024 * 1024;
#pragma unroll
  for (int r = 0; r < 16; ++r) {
    int n = ty + 4 * r;
    dst[(size_t)(n0 + n) * 1024 + k0 + tx] = f2bf(tile[tx][n]);
  }
}

// ---------------- V [B,H,T,D] -> V^T [B,H,D,T], bf16, LDS swizzled ----------------
__global__ __launch_bounds__(256) void vtrans_kernel(const u16* __restrict__ vb,
                                                     u16* __restrict__ vt) {
  __shared__ u16 tile[64 * 64];
  int bh = blockIdx.y, t0 = blockIdx.x * 64;
  size_t base = (size_t)bh * 2048 * 64;
  int tid = threadIdx.x;
#pragma unroll
  for (int it = 0; it < 2; ++it) {
    int chunk = it * 256 + tid;
    int row = chunk >> 3, c8 = (chunk & 7) * 8;  // row = t-rel, c8 = d
    int4 v = *(const int4*)&vb[base + (size_t)(t0 + row) * 64 + c8];
    int addr = (row * 128 + c8 * 2) ^ ((row & 7) << 4);
    *(int4*)((char*)tile + addr) = v;
  }
  __syncthreads();
#pragma unroll
  for (int it = 0; it < 2; ++it) {
    int chunk = it * 256 + tid;
    int d = chunk >> 3, t8 = (chunk & 7) * 8;
    union { u16 u[8]; int4 v; } r;
#pragma unroll
    for (int jj = 0; jj < 8; ++jj) {
      int t = t8 + jj;
      int addr = (t * 128 + d * 2) ^ ((t & 7) << 4);
      r.u[jj] = *(const u16*)((char*)tile + addr);
    }
    *(int4*)&vt[base + (size_t)d * 2048 + t0 + t8] = r.v;
  }
}

// ---------------- 128x128 MFMA GEMM, BK=64 ----------------
// Double-buffered global_load_lds staging (one barrier per K-step), T2 LDS
// swizzle via pre-swizzled global source col (m173), square-ish per-XCD
// block regions (RM x RN blocks per XCD) for L2-resident A/B panels.
template <int EPI>
__global__ __launch_bounds__(256) void gemm128_kernel(
    const u16* __restrict__ A, const u16* __restrict__ Bt, int Kdim,
    int GM, int GN, int RM, int RN,
    u16* __restrict__ qd, u16* __restrict__ kd, u16* __restrict__ vd,
    const float* __restrict__ bq, const float* __restrict__ bk,
    const float* __restrict__ bv, float* __restrict__ outf,
    const float* __restrict__ bias1) {
  __shared__ u16 Alds[2][128 * 64];
  __shared__ u16 Blds[2][128 * 64];
  int tid = threadIdx.x;
  int lane = tid & 63, w = tid >> 6;
  int l15 = lane & 15, lg = lane >> 4;
  // per-XCD rectangular region: xcd = flat&7 owns RM x RN blocks
  int flat = blockIdx.x;
  int xcd = flat & 7, idx = flat >> 3;
  int rnc = GN / RN;
  int rm = (xcd / rnc) * RM, rn = (xcd % rnc) * RN;
  int im = idx % RM, in_ = idx / RM;
  int m0 = (rm + im) * 128, n0 = (rn + in_) * 128;
  int wm = (w >> 1) * 64, wn = (w & 1) * 64;
  int srow = lane >> 3, scol = (lane & 7) * 8;

  auto stage = [&](int buf, int kt) {
#pragma unroll
    for (int j = 0; j < 4; ++j) {
      int issue = w * 4 + j;
      int row = issue * 8 + srow;
      int col = scol ^ ((row & 7) * 8);  // pre-swizzled source column
      gload16(&A[(size_t)(m0 + row) * Kdim + kt + col], &Alds[buf][issue * 512]);
      gload16(&Bt[(size_t)(n0 + row) * Kdim + kt + col], &Blds[buf][issue * 512]);
    }
  };

  f32x4 acc[4][4] = {};
  stage(0, 0);
  int cur = 0;
  for (int kt = 0; kt < Kdim; kt += 64) {
    __syncthreads();  // compiler drains vmcnt -> buf[cur] ready
    if (kt + 64 < Kdim) stage(cur ^ 1, kt + 64);
    __builtin_amdgcn_s_setprio(1);
#pragma unroll
    for (int kk = 0; kk < 2; ++kk) {
      short8 a[4], b[4];
#pragma unroll
      for (int mt = 0; mt < 4; ++mt) {
        int row = wm + mt * 16 + l15;
        int ab = (row * 128 + kk * 64 + lg * 16) ^ ((row & 7) << 4);
        a[mt] = *(const short8*)((char*)Alds[cur] + ab);
      }
#pragma unroll
      for (int nt = 0; nt < 4; ++nt) {
        int row = wn + nt * 16 + l15;
        int ab = (row * 128 + kk * 64 + lg * 16) ^ ((row & 7) << 4);
        b[nt] = *(const short8*)((char*)Blds[cur] + ab);
      }
#pragma unroll
      for (int mt = 0; mt < 4; ++mt)
#pragma unroll
        for (int nt = 0; nt < 4; ++nt)
          acc[mt][nt] = __builtin_amdgcn_mfma_f32_16x16x32_bf16(a[mt], b[nt],
                                                                acc[mt][nt], 0, 0, 0);
    }
    __builtin_amdgcn_s_setprio(0);
    cur ^= 1;
  }
  if (EPI == 0) {
#pragma unroll
    for (int nt = 0; nt < 4; ++nt) {
      int n = n0 + wn + nt * 16 + l15;
      int wi = n >> 10, nn = n & 1023, h = nn >> 6, d = nn & 63;
      u16* dst = (wi == 0) ? qd : (wi == 1) ? kd : vd;
      const float* bb = (wi == 0) ? bq : (wi == 1) ? bk : bv;
      float bval = bb[nn];
#pragma unroll
      for (int mt = 0; mt < 4; ++mt) {
#pragma unroll
        for (int i = 0; i < 4; ++i) {
          int m = m0 + wm + mt * 16 + lg * 4 + i;
          int mb = m >> 11, t = m & 2047;
          dst[((size_t)(mb * 16 + h) * 2048 + t) * 64 + d] = f2bf(acc[mt][nt][i] + bval);
        }
      }
    }
  } else {
#pragma unroll
    for (int nt = 0; nt < 4; ++nt) {
      int n = n0 + wn + nt * 16 + l15;
      float bval = bias1[n];
#pragma unroll
      for (int mt = 0; mt < 4; ++mt) {
#pragma unroll
        for (int i = 0; i < 4; ++i) {
          int m = m0 + wm + mt * 16 + lg * 4 + i;
          outf[(size_t)m * 1024 + n] = acc[mt][nt][i] + bval;
        }
      }
    }
  }
}

// ---------------- causal flash attention, swapped-operand MFMA ----------------
// 1024 blocks: one 64-row q-tile each (4 waves x 16 rows), longest-first
// (qt = 31 - flat>>5). head = flat&31 keeps flat%8 == head%8 -> each XCD
// serves 4 heads, K+V^T L2-resident. Double-buffered global_load_lds staging,
// one barrier per tile. T13 defer-max (THR=8) skips O-rescale on most tiles.
__global__ __launch_bounds__(256) void fattn_kernel(const u16* __restrict__ qb,
                                                    const u16* __restrict__ kb,
                                                    const u16* __restrict__ vt,
                                                    u16* __restrict__ y) {
  __shared__ u16 Klds[2][64 * 64];
  __shared__ u16 Vlds[2][64 * 64];   // V^T: [d][kv], swizzled
  __shared__ u16 Plds[4][16 * 64];
  int tid = threadIdx.x, lane = tid & 63, w = tid >> 6;
  int l15 = lane & 15, lg = lane >> 4;
  int flat = blockIdx.x;
  int bh = flat & 31;
  int qt = 31 - (flat >> 5);          // longest-first dispatch
  size_t base = (size_t)bh * 2048 * 64;
  int mb = bh >> 4, h = bh & 15;
  const float SC = 0.125f * 1.44269504088896340736f;  // fold /sqrt(64), log2(e)
  const float NINF = -__builtin_inff();
  int cb = 0;

  int qw = qt * 64 + w * 16;
  int qr = qw + l15;
  short8 qf[2];
#pragma unroll
  for (int kk = 0; kk < 2; ++kk)
    qf[kk] = *(const short8*)&qb[base + (size_t)qr * 64 + kk * 32 + lg * 8];
  f32x4 o[4] = {};
  float mrow = NINF, lrow = 0.f;
  {  // prologue stage tile 0 into cb
#pragma unroll
    for (int it = 0; it < 2; ++it) {
      int chunk = it * 256 + tid;
      int row = chunk >> 3;
      int col = ((chunk & 7) * 8) ^ ((row & 7) << 3);
      int ldsoff = (it * 256 + w * 64) * 8;
      gload16(&kb[base + (size_t)row * 64 + col], &Klds[cb][ldsoff]);
      gload16(&vt[base + (size_t)row * 2048 + col], &Vlds[cb][ldsoff]);
    }
  }
  int ntiles = qt + 1;
  for (int j = 0; j < ntiles; ++j) {
    __syncthreads();  // compiler drains vmcnt before barrier: buf[cb] ready
    if (j + 1 < ntiles) {  // prefetch next tile into cb^1
      int k0 = (j + 1) * 64;
      int nb = cb ^ 1;
#pragma unroll
      for (int it = 0; it < 2; ++it) {
        int chunk = it * 256 + tid;
        int row = chunk >> 3;
        int col = ((chunk & 7) * 8) ^ ((row & 7) << 3);
        int ldsoff = (it * 256 + w * 64) * 8;
        gload16(&kb[base + (size_t)(k0 + row) * 64 + col], &Klds[nb][ldsoff]);
        gload16(&vt[base + (size_t)row * 2048 + k0 + col], &Vlds[nb][ldsoff]);
      }
    }
    // S^T = K Q^T  (swapped operands)
    f32x4 s[4] = {};
    __builtin_amdgcn_s_setprio(1);
#pragma unroll
    for (int kk = 0; kk < 2; ++kk) {
      short8 ka[4];
#pragma unroll
      for (int nt = 0; nt < 4; ++nt) {
        int row = nt * 16 + l15;
        int addr = (row * 128 + kk * 64 + lg * 16) ^ ((row & 7) << 4);
        ka[nt] = *(const short8*)((char*)Klds[cb] + addr);
      }
#pragma unroll
      for (int nt = 0; nt < 4; ++nt)
        s[nt] = __builtin_amdgcn_mfma_f32_16x16x32_bf16(ka[nt], qf[kk], s[nt], 0, 0, 0);
    }
    __builtin_amdgcn_s_setprio(0);
    // in-lane online softmax for q-row qr (lane-local over 16 k values)
    float sv[16];
    if (j == qt) {
#pragma unroll
      for (int nt = 0; nt < 4; ++nt)
#pragma unroll
        for (int i = 0; i < 4; ++i) {
          int ka_ = j * 64 + nt * 16 + lg * 4 + i;
          sv[nt * 4 + i] = (ka_ > qr) ? NINF : s[nt][i] * SC;
        }
    } else {
#pragma unroll
      for (int nt = 0; nt < 4; ++nt)
#pragma unroll
        for (int i = 0; i < 4; ++i) sv[nt * 4 + i] = s[nt][i] * SC;
    }
    float m0_ = fmaxf(fmaxf(fmaxf(sv[0], sv[1]), fmaxf(sv[2], sv[3])),
                      fmaxf(fmaxf(sv[4], sv[5]), fmaxf(sv[6], sv[7])));
    float m1_ = fmaxf(fmaxf(fmaxf(sv[8], sv[9]), fmaxf(sv[10], sv[11])),
                      fmaxf(fmaxf(sv[12], sv[13]), fmaxf(sv[14], sv[15])));
    float tmax = fmaxf(m0_, m1_);
    tmax = fmaxf(tmax, __shfl_xor(tmax, 16));
    tmax = fmaxf(tmax, __shfl_xor(tmax, 32));
    // T13 defer-max: only rescale when the tile max overshoots the running
    // max by >8 (P then bounded by 2^8 -- fine in bf16/f32).
    if (!__all(tmax <= mrow + 8.f)) {
      float vmax = fmaxf(tmax, mrow);
      float scale = exp2f(mrow - vmax);
      mrow = vmax;
      lrow *= scale;
#pragma unroll
      for (int dn = 0; dn < 4; ++dn) o[dn] *= scale;
    }
#pragma unroll
    for (int u = 0; u < 16; ++u) sv[u] = exp2f(sv[u] - mrow);
    float r0 = ((sv[0] + sv[1]) + (sv[2] + sv[3])) + ((sv[4] + sv[5]) + (sv[6] + sv[7]));
    float r1 = ((sv[8] + sv[9]) + (sv[10] + sv[11])) + ((sv[12] + sv[13]) + (sv[14] + sv[15]));
    float rsum = r0 + r1;
    rsum += __shfl_xor(rsum, 16);
    rsum += __shfl_xor(rsum, 32);
    lrow += rsum;
    // P[q][k] -> LDS, packed b64 (4 consecutive k per write)
#pragma unroll
    for (int nt = 0; nt < 4; ++nt) {
      unsigned plo = cvtpk(sv[nt * 4 + 0], sv[nt * 4 + 1]);
      unsigned phi = cvtpk(sv[nt * 4 + 2], sv[nt * 4 + 3]);
      int addr = (l15 * 128 + nt * 32 + lg * 8) ^ ((l15 & 7) << 4);
      *(uint2*)((char*)Plds[w] + addr) = make_uint2(plo, phi);
    }
    // O^T += V^T P^T  (swapped operands)
    __builtin_amdgcn_s_setprio(1);
#pragma unroll
    for (int kk = 0; kk < 2; ++kk) {
      int paddr = (l15 * 128 + kk * 64 + lg * 16) ^ ((l15 & 7) << 4);
      short8 ap = *(const short8*)((char*)Plds[w] + paddr);
#pragma unroll
      for (int dn = 0; dn < 4; ++dn) {
        int row = dn * 16 + l15;
        int addr = (row * 128 + kk * 64 + lg * 16) ^ ((row & 7) << 4);
        short8 bv_ = *(const short8*)((char*)Vlds[cb] + addr);
        o[dn] = __builtin_amdgcn_mfma_f32_16x16x32_bf16(bv_, ap, o[dn], 0, 0, 0);
      }
    }
    __builtin_amdgcn_s_setprio(0);
    cb ^= 1;
  }
  // normalize + write y [B,T,C] bf16; O^T frag: d = dn*16+lg*4+i, q = qr
  float inv = 1.f / lrow;
  size_t rb = ((size_t)(mb * 2048 + qr)) * 1024 + (size_t)h * 64;
#pragma unroll
  for (int dn = 0; dn < 4; ++dn) {
    unsigned lo = cvtpk(o[dn][0] * inv, o[dn][1] * inv);
    unsigned hi = cvtpk(o[dn][2] * inv, o[dn][3] * inv);
    *(uint2*)&y[rb + dn * 16 + lg * 4] = make_uint2(lo, hi);
  }
}

extern "C" void kernel_launch(void* const* d_in, const int* in_sizes, int n_in,
                              void* d_out, int out_size, void* d_ws, size_t ws_size,
                              hipStream_t stream) {
  const float* x  = (const float*)d_in[0];
  const float* Wq = (const float*)d_in[1];
  const float* bq = (const float*)d_in[2];
  const float* Wk = (const float*)d_in[3];
  const float* bk = (const float*)d_in[4];
  const float* Wv = (const float*)d_in[5];
  const float* bv = (const float*)d_in[6];
  const float* Wp = (const float*)d_in[7];
  const float* bp = (const float*)d_in[8];
  float* out = (float*)d_out;
  char* ws = (char*)d_ws;
  u16* xb   = (u16*)(ws);
  u16* wt   = (u16*)(ws + ((size_t)8 << 20));
  u16* qbuf = (u16*)(ws + ((size_t)16 << 20));
  u16* kbuf = (u16*)(ws + ((size_t)24 << 20));
  u16* vbuf = (u16*)(ws + ((size_t)32 << 20));
  u16* ybuf = (u16*)(ws + ((size_t)40 << 20));
  u16* vtb  = xb;  // x_bf16 region is dead after the QKV GEMM; reuse for V^T

  cvt_x_kernel<<<dim3(2048), dim3(256), 0, stream>>>(x, xb);
  wtrans_kernel<<<dim3(16, 16, 4), dim3(256), 0, stream>>>(Wq, Wk, Wv, Wp, wt);
  // QKV: M=4096 (GM=32), N=3072 (GN=24); per-XCD region 8x12 blocks
  gemm128_kernel<0><<<dim3(768), dim3(256), 0, stream>>>(
      xb, wt, 1024, 32, 24, 8, 12,
      qbuf, kbuf, vbuf, bq, bk, bv, (float*)nullptr, (const float*)nullptr);
  vtrans_kernel<<<dim3(32, 32), dim3(256), 0, stream>>>(vbuf, vtb);
  fattn_kernel<<<dim3(1024), dim3(256), 0, stream>>>(qbuf, kbuf, vtb, ybuf);
  // proj: M=4096 (GM=32), N=1024 (GN=8); per-XCD region 8x4 blocks
  gemm128_kernel<1><<<dim3(256), dim3(256), 0, stream>>>(
      ybuf, wt + (size_t)3 * 1024 * 1024, 1024, 32, 8, 8, 4,
      (u16*)nullptr, (u16*)nullptr, (u16*)nullptr,
      (const float*)nullptr, (const float*)nullptr, (const float*)nullptr, out, bp);
  (void)in_sizes; (void)n_in; (void)out_size; (void)ws_size;
}

// Round 6
// 116.947 us; speedup vs baseline: 1.9697x; 1.1104x over previous
//
#include <hip/hip_runtime.h>
#include <hip/hip_bf16.h>
#include <stdint.h>

typedef unsigned short u16;
typedef __attribute__((ext_vector_type(8))) short short8;
typedef __attribute__((ext_vector_type(4))) float f32x4;

// ws layout (bytes): [0,8M) x_bf16 [8M,16M) Wt(4x1Mx2B) [16M,24M) q
// [24M,32M) k [32M,40M) v^T [B,H,D,T] [40M,48M) y
static __device__ __forceinline__ u16 f2bf(float f) {
  unsigned u = __builtin_bit_cast(unsigned, f);
  u += 0x7fffu + ((u >> 16) & 1u);
  return (u16)(u >> 16);
}

static __device__ __forceinline__ unsigned cvtpk(float lo, float hi) {
  unsigned r;
  asm("v_cvt_pk_bf16_f32 %0, %1, %2" : "=v"(r) : "v"(lo), "v"(hi));
  return r;
}

static __device__ __forceinline__ void gload16(const u16* g, u16* l) {
  __builtin_amdgcn_global_load_lds(
      (__attribute__((address_space(1))) void*)const_cast<u16*>(g),
      (__attribute__((address_space(3))) void*)l, 16, 0, 0);
}

// ---------------- fused prep: x fp32->bf16 (blocks 0..2047) +
//                  W [k][n] fp32 -> Wt [n][k] bf16 (blocks 2048..3071) ----------
__global__ __launch_bounds__(256) void prep_kernel(
    const float* __restrict__ x, const float* __restrict__ Wq,
    const float* __restrict__ Wk, const float* __restrict__ Wv,
    const float* __restrict__ Wp, u16* __restrict__ xb, u16* __restrict__ wt) {
  __shared__ float tile[64][65];
  int b = blockIdx.x;
  if (b < 2048) {
    size_t i = (size_t)b * 256 + threadIdx.x;  // 8 floats per thread
    const float4* xp = (const float4*)x + i * 2;
    float4 a = xp[0], v = xp[1];
    union { u16 u[8]; int4 q; } r;
    r.u[0] = f2bf(a.x); r.u[1] = f2bf(a.y); r.u[2] = f2bf(a.z); r.u[3] = f2bf(a.w);
    r.u[4] = f2bf(v.x); r.u[5] = f2bf(v.y); r.u[6] = f2bf(v.z); r.u[7] = f2bf(v.w);
    *(int4*)(xb + i * 8) = r.q;
  } else {
    int wb = b - 2048;
    int wz = wb >> 8, r8 = wb & 255;
    const float* W = (wz == 0) ? Wq : (wz == 1) ? Wk : (wz == 2) ? Wv : Wp;
    int n0 = (r8 & 15) * 64, k0 = (r8 >> 4) * 64;
    int tx = threadIdx.x & 63, ty = threadIdx.x >> 6;
#pragma unroll
    for (int r = 0; r < 16; ++r)
      tile[ty + 4 * r][tx] = W[(size_t)(k0 + ty + 4 * r) * 1024 + n0 + tx];
    __syncthreads();
    u16* dst = wt + (size_t)wz * 1024 * 1024;
#pragma unroll
    for (int r = 0; r < 16; ++r) {
      int n = ty + 4 * r;
      dst[(size_t)(n0 + n) * 1024 + k0 + tx] = f2bf(tile[tx][n]);
    }
  }
}

// ---------------- 128x128 MFMA GEMM, BK=64 ----------------
// Double-buffered global_load_lds staging (one barrier per K-step), T2 LDS
// swizzle via pre-swizzled global source col (m173), square-ish per-XCD
// block regions (RM x RN blocks per XCD) for L2-resident A/B panels.
// EPI==0: q,k -> [B,H,T,D]; v -> transposed [B,H,D,T] (uint2 stores).
template <int EPI>
__global__ __launch_bounds__(256) void gemm128_kernel(
    const u16* __restrict__ A, const u16* __restrict__ Bt, int Kdim,
    int GM, int GN, int RM, int RN,
    u16* __restrict__ qd, u16* __restrict__ kd, u16* __restrict__ vd,
    const float* __restrict__ bq, const float* __restrict__ bk,
    const float* __restrict__ bv, float* __restrict__ outf,
    const float* __restrict__ bias1) {
  __shared__ u16 Alds[2][128 * 64];
  __shared__ u16 Blds[2][128 * 64];
  int tid = threadIdx.x;
  int lane = tid & 63, w = tid >> 6;
  int l15 = lane & 15, lg = lane >> 4;
  int flat = blockIdx.x;
  int xcd = flat & 7, idx = flat >> 3;
  int rnc = GN / RN;
  int rm = (xcd / rnc) * RM, rn = (xcd % rnc) * RN;
  int im = idx % RM, in_ = idx / RM;
  int m0 = (rm + im) * 128, n0 = (rn + in_) * 128;
  int wm = (w >> 1) * 64, wn = (w & 1) * 64;
  int srow = lane >> 3, scol = (lane & 7) * 8;

  auto stage = [&](int buf, int kt) {
#pragma unroll
    for (int j = 0; j < 4; ++j) {
      int issue = w * 4 + j;
      int row = issue * 8 + srow;
      int col = scol ^ ((row & 7) * 8);  // pre-swizzled source column
      gload16(&A[(size_t)(m0 + row) * Kdim + kt + col], &Alds[buf][issue * 512]);
      gload16(&Bt[(size_t)(n0 + row) * Kdim + kt + col], &Blds[buf][issue * 512]);
    }
  };

  f32x4 acc[4][4] = {};
  stage(0, 0);
  int cur = 0;
  for (int kt = 0; kt < Kdim; kt += 64) {
    __syncthreads();  // compiler drains vmcnt -> buf[cur] ready
    if (kt + 64 < Kdim) stage(cur ^ 1, kt + 64);
    __builtin_amdgcn_s_setprio(1);
#pragma unroll
    for (int kk = 0; kk < 2; ++kk) {
      short8 a[4], b[4];
#pragma unroll
      for (int mt = 0; mt < 4; ++mt) {
        int row = wm + mt * 16 + l15;
        int ab = (row * 128 + kk * 64 + lg * 16) ^ ((row & 7) << 4);
        a[mt] = *(const short8*)((char*)Alds[cur] + ab);
      }
#pragma unroll
      for (int nt = 0; nt < 4; ++nt) {
        int row = wn + nt * 16 + l15;
        int ab = (row * 128 + kk * 64 + lg * 16) ^ ((row & 7) << 4);
        b[nt] = *(const short8*)((char*)Blds[cur] + ab);
      }
#pragma unroll
      for (int mt = 0; mt < 4; ++mt)
#pragma unroll
        for (int nt = 0; nt < 4; ++nt)
          acc[mt][nt] = __builtin_amdgcn_mfma_f32_16x16x32_bf16(a[mt], b[nt],
                                                                acc[mt][nt], 0, 0, 0);
    }
    __builtin_amdgcn_s_setprio(0);
    cur ^= 1;
  }
  if (EPI == 0) {
#pragma unroll
    for (int nt = 0; nt < 4; ++nt) {
      int n = n0 + wn + nt * 16 + l15;
      int wi = n >> 10, nn = n & 1023, h = nn >> 6, d = nn & 63;
      const float* bb = (wi == 0) ? bq : (wi == 1) ? bk : bv;
      float bval = bb[nn];
      if (wi == 2) {  // V: write transposed [B,H,D,T], 4 consecutive t -> uint2
#pragma unroll
        for (int mt = 0; mt < 4; ++mt) {
          int m = m0 + wm + mt * 16 + lg * 4;
          int mb = m >> 11, t = m & 2047;
          unsigned lo = cvtpk(acc[mt][nt][0] + bval, acc[mt][nt][1] + bval);
          unsigned hi = cvtpk(acc[mt][nt][2] + bval, acc[mt][nt][3] + bval);
          *(uint2*)&vd[((size_t)(mb * 16 + h) * 64 + d) * 2048 + t] =
              make_uint2(lo, hi);
        }
      } else {
        u16* dst = (wi == 0) ? qd : kd;
#pragma unroll
        for (int mt = 0; mt < 4; ++mt) {
#pragma unroll
          for (int i = 0; i < 4; ++i) {
            int m = m0 + wm + mt * 16 + lg * 4 + i;
            int mb = m >> 11, t = m & 2047;
            dst[((size_t)(mb * 16 + h) * 2048 + t) * 64 + d] =
                f2bf(acc[mt][nt][i] + bval);
          }
        }
      }
    }
  } else {
#pragma unroll
    for (int nt = 0; nt < 4; ++nt) {
      int n = n0 + wn + nt * 16 + l15;
      float bval = bias1[n];
#pragma unroll
      for (int mt = 0; mt < 4; ++mt) {
#pragma unroll
        for (int i = 0; i < 4; ++i) {
          int m = m0 + wm + mt * 16 + lg * 4 + i;
          outf[(size_t)m * 1024 + n] = acc[mt][nt][i] + bval;
        }
      }
    }
  }
}

// ---------------- causal flash attention, swapped-operand MFMA ----------------
// 1024 blocks: one 64-row q-tile each (4 waves x 16 rows), longest-first.
// head = flat&31 keeps flat%8 == head%8 -> 4 heads/XCD, K+V^T L2-resident.
// Double-buffered global_load_lds staging, one barrier per tile.
// Softmax: defer-max with PER-LANE partial max (ballot-equivalent to full max
// -> zero cross-lane ops on the common path); lrow kept as per-lane partial,
// reduced once at the end; exp arg folded into one FMA.
__global__ __launch_bounds__(256) void fattn_kernel(const u16* __restrict__ qb,
                                                    const u16* __restrict__ kb,
                                                    const u16* __restrict__ vt,
                                                    u16* __restrict__ y) {
  __shared__ u16 Klds[2][64 * 64];
  __shared__ u16 Vlds[2][64 * 64];   // V^T: [d][kv], swizzled
  __shared__ u16 Plds[4][16 * 64];
  int tid = threadIdx.x, lane = tid & 63, w = tid >> 6;
  int l15 = lane & 15, lg = lane >> 4;
  int flat = blockIdx.x;
  int bh = flat & 31;
  int qt = 31 - (flat >> 5);          // longest-first dispatch
  size_t base = (size_t)bh * 2048 * 64;
  int mb = bh >> 4, h = bh & 15;
  const float SC = 0.125f * 1.44269504088896340736f;  // fold /sqrt(64), log2(e)
  const float NINF = -__builtin_inff();
  int cb = 0;

  int qw = qt * 64 + w * 16;
  int qr = qw + l15;
  short8 qf[2];
#pragma unroll
  for (int kk = 0; kk < 2; ++kk)
    qf[kk] = *(const short8*)&qb[base + (size_t)qr * 64 + kk * 32 + lg * 8];
  f32x4 o[4] = {};
  float mrow = NINF, lrow = 0.f;
  {  // prologue stage tile 0 into cb
#pragma unroll
    for (int it = 0; it < 2; ++it) {
      int chunk = it * 256 + tid;
      int row = chunk >> 3;
      int col = ((chunk & 7) * 8) ^ ((row & 7) << 3);
      int ldsoff = (it * 256 + w * 64) * 8;
      gload16(&kb[base + (size_t)row * 64 + col], &Klds[cb][ldsoff]);
      gload16(&vt[base + (size_t)row * 2048 + col], &Vlds[cb][ldsoff]);
    }
  }
  int ntiles = qt + 1;
  for (int j = 0; j < ntiles; ++j) {
    __syncthreads();  // compiler drains vmcnt before barrier: buf[cb] ready
    if (j + 1 < ntiles) {  // prefetch next tile into cb^1
      int k0p = (j + 1) * 64;
      int nb = cb ^ 1;
#pragma unroll
      for (int it = 0; it < 2; ++it) {
        int chunk = it * 256 + tid;
        int row = chunk >> 3;
        int col = ((chunk & 7) * 8) ^ ((row & 7) << 3);
        int ldsoff = (it * 256 + w * 64) * 8;
        gload16(&kb[base + (size_t)(k0p + row) * 64 + col], &Klds[nb][ldsoff]);
        gload16(&vt[base + (size_t)row * 2048 + k0p + col], &Vlds[nb][ldsoff]);
      }
    }
    // S^T = K Q^T  (swapped operands)
    f32x4 s[4] = {};
    __builtin_amdgcn_s_setprio(1);
#pragma unroll
    for (int kk = 0; kk < 2; ++kk) {
      short8 ka[4];
#pragma unroll
      for (int nt = 0; nt < 4; ++nt) {
        int row = nt * 16 + l15;
        int addr = (row * 128 + kk * 64 + lg * 16) ^ ((row & 7) << 4);
        ka[nt] = *(const short8*)((char*)Klds[cb] + addr);
      }
#pragma unroll
      for (int nt = 0; nt < 4; ++nt)
        s[nt] = __builtin_amdgcn_mfma_f32_16x16x32_bf16(ka[nt], qf[kk], s[nt], 0, 0, 0);
    }
    __builtin_amdgcn_s_setprio(0);
    // masked raw scores (scale folded later)
    float rs[16];
    if (j == qt) {
      int k0 = j * 64;
#pragma unroll
      for (int nt = 0; nt < 4; ++nt)
#pragma unroll
        for (int i = 0; i < 4; ++i) {
          int ka_ = k0 + nt * 16 + lg * 4 + i;
          rs[nt * 4 + i] = (ka_ > qr) ? NINF : s[nt][i];
        }
    } else {
#pragma unroll
      for (int nt = 0; nt < 4; ++nt)
#pragma unroll
        for (int i = 0; i < 4; ++i) rs[nt * 4 + i] = s[nt][i];
    }
    // per-lane partial max; ballot over partials == ballot over full max
    float rmax = fmaxf(
        fmaxf(fmaxf(fmaxf(rs[0], rs[1]), fmaxf(rs[2], rs[3])),
              fmaxf(fmaxf(rs[4], rs[5]), fmaxf(rs[6], rs[7]))),
        fmaxf(fmaxf(fmaxf(rs[8], rs[9]), fmaxf(rs[10], rs[11])),
              fmaxf(fmaxf(rs[12], rs[13]), fmaxf(rs[14], rs[15]))));
    float tmax = rmax * SC;
    if (!__all(tmax <= mrow + 8.f)) {  // rare: full reduce + rescale
      float t2 = fmaxf(tmax, __shfl_xor(tmax, 16));
      t2 = fmaxf(t2, __shfl_xor(t2, 32));
      float vmax = fmaxf(t2, mrow);
      float scale = exp2f(mrow - vmax);
      mrow = vmax;
      lrow *= scale;
#pragma unroll
      for (int dn = 0; dn < 4; ++dn) o[dn] *= scale;
    }
    float p[16];
#pragma unroll
    for (int u = 0; u < 16; ++u) p[u] = exp2f(fmaf(rs[u], SC, -mrow));
    float r0 = ((p[0] + p[1]) + (p[2] + p[3])) + ((p[4] + p[5]) + (p[6] + p[7]));
    float r1 = ((p[8] + p[9]) + (p[10] + p[11])) + ((p[12] + p[13]) + (p[14] + p[15]));
    lrow += r0 + r1;  // per-lane partial; reduced after the loop
    // P[q][k] -> LDS, packed b64 (4 consecutive k per write)
#pragma unroll
    for (int nt = 0; nt < 4; ++nt) {
      unsigned plo = cvtpk(p[nt * 4 + 0], p[nt * 4 + 1]);
      unsigned phi = cvtpk(p[nt * 4 + 2], p[nt * 4 + 3]);
      int addr = (l15 * 128 + nt * 32 + lg * 8) ^ ((l15 & 7) << 4);
      *(uint2*)((char*)Plds[w] + addr) = make_uint2(plo, phi);
    }
    // O^T += V^T P^T  (swapped operands)
    __builtin_amdgcn_s_setprio(1);
#pragma unroll
    for (int kk = 0; kk < 2; ++kk) {
      int paddr = (l15 * 128 + kk * 64 + lg * 16) ^ ((l15 & 7) << 4);
      short8 ap = *(const short8*)((char*)Plds[w] + paddr);
#pragma unroll
      for (int dn = 0; dn < 4; ++dn) {
        int row = dn * 16 + l15;
        int addr = (row * 128 + kk * 64 + lg * 16) ^ ((row & 7) << 4);
        short8 bv_ = *(const short8*)((char*)Vlds[cb] + addr);
        o[dn] = __builtin_amdgcn_mfma_f32_16x16x32_bf16(bv_, ap, o[dn], 0, 0, 0);
      }
    }
    __builtin_amdgcn_s_setprio(0);
    cb ^= 1;
  }
  // combine lrow partials across the 4 lane-groups of each q-row
  lrow += __shfl_xor(lrow, 16);
  lrow += __shfl_xor(lrow, 32);
  float inv = 1.f / lrow;
  size_t rb = ((size_t)(mb * 2048 + qr)) * 1024 + (size_t)h * 64;
#pragma unroll
  for (int dn = 0; dn < 4; ++dn) {
    unsigned lo = cvtpk(o[dn][0] * inv, o[dn][1] * inv);
    unsigned hi = cvtpk(o[dn][2] * inv, o[dn][3] * inv);
    *(uint2*)&y[rb + dn * 16 + lg * 4] = make_uint2(lo, hi);
  }
}

extern "C" void kernel_launch(void* const* d_in, const int* in_sizes, int n_in,
                              void* d_out, int out_size, void* d_ws, size_t ws_size,
                              hipStream_t stream) {
  const float* x  = (const float*)d_in[0];
  const float* Wq = (const float*)d_in[1];
  const float* bq = (const float*)d_in[2];
  const float* Wk = (const float*)d_in[3];
  const float* bk = (const float*)d_in[4];
  const float* Wv = (const float*)d_in[5];
  const float* bv = (const float*)d_in[6];
  const float* Wp = (const float*)d_in[7];
  const float* bp = (const float*)d_in[8];
  float* out = (float*)d_out;
  char* ws = (char*)d_ws;
  u16* xb   = (u16*)(ws);
  u16* wt   = (u16*)(ws + ((size_t)8 << 20));
  u16* qbuf = (u16*)(ws + ((size_t)16 << 20));
  u16* kbuf = (u16*)(ws + ((size_t)24 << 20));
  u16* vtb  = (u16*)(ws + ((size_t)32 << 20));  // V^T written by QKV epilogue
  u16* ybuf = (u16*)(ws + ((size_t)40 << 20));

  prep_kernel<<<dim3(3072), dim3(256), 0, stream>>>(x, Wq, Wk, Wv, Wp, xb, wt);
  // QKV: M=4096 (GM=32), N=3072 (GN=24); per-XCD region 8x12 blocks
  gemm128_kernel<0><<<dim3(768), dim3(256), 0, stream>>>(
      xb, wt, 1024, 32, 24, 8, 12,
      qbuf, kbuf, vtb, bq, bk, bv, (float*)nullptr, (const float*)nullptr);
  fattn_kernel<<<dim3(1024), dim3(256), 0, stream>>>(qbuf, kbuf, vtb, ybuf);
  // proj: M=4096 (GM=32), N=1024 (GN=8); per-XCD region 8x4 blocks
  gemm128_kernel<1><<<dim3(256), dim3(256), 0, stream>>>(
      ybuf, wt + (size_t)3 * 1024 * 1024, 1024, 32, 8, 8, 4,
      (u16*)nullptr, (u16*)nullptr, (u16*)nullptr,
      (const float*)nullptr, (const float*)nullptr, (const float*)nullptr, out, bp);
  (void)in_sizes; (void)n_in; (void)out_size; (void)ws_size;
}

// Round 7
// 113.666 us; speedup vs baseline: 2.0265x; 1.0289x over previous
//
#include <hip/hip_runtime.h>
#include <hip/hip_bf16.h>
#include <stdint.h>

typedef unsigned short u16;
typedef __attribute__((ext_vector_type(8))) short short8;
typedef __attribute__((ext_vector_type(4))) float f32x4;

// ws layout (bytes): [0,8M) x_bf16 [8M,16M) Wt(4x1Mx2B) [16M,24M) q
// [24M,32M) k [32M,40M) v^T [B,H,D,T] [40M,48M) y
static __device__ __forceinline__ u16 f2bf(float f) {
  unsigned u = __builtin_bit_cast(unsigned, f);
  u += 0x7fffu + ((u >> 16) & 1u);
  return (u16)(u >> 16);
}

static __device__ __forceinline__ unsigned cvtpk(float lo, float hi) {
  unsigned r;
  asm("v_cvt_pk_bf16_f32 %0, %1, %2" : "=v"(r) : "v"(lo), "v"(hi));
  return r;
}

static __device__ __forceinline__ void gload16(const u16* g, u16* l) {
  __builtin_amdgcn_global_load_lds(
      (__attribute__((address_space(1))) void*)const_cast<u16*>(g),
      (__attribute__((address_space(3))) void*)l, 16, 0, 0);
}

// ---------------- fused prep: x fp32->bf16 (blocks 0..2047) +
//                  W [k][n] fp32 -> Wt [n][k] bf16 (blocks 2048..3071) ----------
__global__ __launch_bounds__(256) void prep_kernel(
    const float* __restrict__ x, const float* __restrict__ Wq,
    const float* __restrict__ Wk, const float* __restrict__ Wv,
    const float* __restrict__ Wp, u16* __restrict__ xb, u16* __restrict__ wt) {
  __shared__ float tile[64][65];
  int b = blockIdx.x;
  if (b < 2048) {
    size_t i = (size_t)b * 256 + threadIdx.x;  // 8 floats per thread
    const float4* xp = (const float4*)x + i * 2;
    float4 a = xp[0], v = xp[1];
    union { u16 u[8]; int4 q; } r;
    r.u[0] = f2bf(a.x); r.u[1] = f2bf(a.y); r.u[2] = f2bf(a.z); r.u[3] = f2bf(a.w);
    r.u[4] = f2bf(v.x); r.u[5] = f2bf(v.y); r.u[6] = f2bf(v.z); r.u[7] = f2bf(v.w);
    *(int4*)(xb + i * 8) = r.q;
  } else {
    int wb = b - 2048;
    int wz = wb >> 8, r8 = wb & 255;
    const float* W = (wz == 0) ? Wq : (wz == 1) ? Wk : (wz == 2) ? Wv : Wp;
    int n0 = (r8 & 15) * 64, k0 = (r8 >> 4) * 64;
    int tx = threadIdx.x & 63, ty = threadIdx.x >> 6;
#pragma unroll
    for (int r = 0; r < 16; ++r)
      tile[ty + 4 * r][tx] = W[(size_t)(k0 + ty + 4 * r) * 1024 + n0 + tx];
    __syncthreads();
    u16* dst = wt + (size_t)wz * 1024 * 1024;
#pragma unroll
    for (int r = 0; r < 16; ++r) {
      int n = ty + 4 * r;
      dst[(size_t)(n0 + n) * 1024 + k0 + tx] = f2bf(tile[tx][n]);
    }
  }
}

// ---------------- 128x128 MFMA GEMM, BK=64 ----------------
// Double-buffered global_load_lds staging, T2 swizzle via pre-swizzled source
// col; all staging pointers advance by constant stride per K-step; all LDS
// read addresses hoisted (base + nt*2048 immediate; row&7 == l15&7 makes the
// XOR loop-invariant). Square-ish per-XCD block regions for L2 residency.
// EPI==0: q,k -> [B,H,T,D]; v -> transposed [B,H,D,T] (uint2 stores).
template <int EPI>
__global__ __launch_bounds__(256, 2) void gemm128_kernel(
    const u16* __restrict__ A, const u16* __restrict__ Bt, int Kdim,
    int GM, int GN, int RM, int RN,
    u16* __restrict__ qd, u16* __restrict__ kd, u16* __restrict__ vd,
    const float* __restrict__ bq, const float* __restrict__ bk,
    const float* __restrict__ bv, float* __restrict__ outf,
    const float* __restrict__ bias1) {
  __shared__ u16 Alds[2 * 8192];
  __shared__ u16 Blds[2 * 8192];
  int tid = threadIdx.x;
  int lane = tid & 63, w = tid >> 6;
  int l15 = lane & 15, lg = lane >> 4;
  int flat = blockIdx.x;
  int xcd = flat & 7, idx = flat >> 3;
  int rnc = GN / RN;
  int rm = (xcd / rnc) * RM, rn = (xcd % rnc) * RN;
  int im = idx % RM, in_ = idx / RM;
  int m0 = (rm + im) * 128, n0 = (rn + in_) * 128;
  int wm = (w >> 1) * 64, wn = (w & 1) * 64;
  int srow = lane >> 3;
  int colsw = ((lane & 7) * 8) ^ ((srow & 7) * 8);  // pre-swizzled source col

  // staging pointers (advance +64 per K-step) and LDS dest offsets
  const u16* pA[4];
  const u16* pB[4];
  int dls[4];
#pragma unroll
  for (int j = 0; j < 4; ++j) {
    int issue = w * 4 + j;
    int row = issue * 8 + srow;
    pA[j] = A + (size_t)(m0 + row) * Kdim + colsw;
    pB[j] = Bt + (size_t)(n0 + row) * Kdim + colsw;
    dls[j] = issue * 512;
  }
  // hoisted LDS read bases
  int kx = (l15 & 7) << 4;
  int ofs0 = (lg * 16) ^ kx, ofs1 = (64 + lg * 16) ^ kx;
  int rbA = (wm + l15) * 128, rbB = (wn + l15) * 128;

  f32x4 acc[4][4] = {};
  {  // prologue: stage K-step 0 into buf 0
#pragma unroll
    for (int j = 0; j < 4; ++j) {
      gload16(pA[j], Alds + dls[j]);
      gload16(pB[j], Blds + dls[j]);
      pA[j] += 64; pB[j] += 64;
    }
  }
  int cur = 0;
  for (int kt = 0; kt < Kdim; kt += 64) {
    __syncthreads();  // compiler drains vmcnt -> buf[cur] ready
    if (kt + 64 < Kdim) {
      u16* Ad = Alds + (cur ^ 1) * 8192;
      u16* Bd = Blds + (cur ^ 1) * 8192;
#pragma unroll
      for (int j = 0; j < 4; ++j) {
        gload16(pA[j], Ad + dls[j]);
        gload16(pB[j], Bd + dls[j]);
        pA[j] += 64; pB[j] += 64;
      }
    }
    const char* Al = (const char*)Alds + cur * 16384;
    const char* Bl = (const char*)Blds + cur * 16384;
    __builtin_amdgcn_s_setprio(1);
#pragma unroll
    for (int kk = 0; kk < 2; ++kk) {
      int o_ = kk ? ofs1 : ofs0;
      short8 a[4], b[4];
#pragma unroll
      for (int mt = 0; mt < 4; ++mt)
        a[mt] = *(const short8*)(Al + (rbA + o_) + mt * 2048);
#pragma unroll
      for (int nt = 0; nt < 4; ++nt)
        b[nt] = *(const short8*)(Bl + (rbB + o_) + nt * 2048);
#pragma unroll
      for (int mt = 0; mt < 4; ++mt)
#pragma unroll
        for (int nt = 0; nt < 4; ++nt)
          acc[mt][nt] = __builtin_amdgcn_mfma_f32_16x16x32_bf16(a[mt], b[nt],
                                                                acc[mt][nt], 0, 0, 0);
    }
    __builtin_amdgcn_s_setprio(0);
    cur ^= 1;
  }
  if (EPI == 0) {
#pragma unroll
    for (int nt = 0; nt < 4; ++nt) {
      int n = n0 + wn + nt * 16 + l15;
      int wi = n >> 10, nn = n & 1023, h = nn >> 6, d = nn & 63;
      const float* bb = (wi == 0) ? bq : (wi == 1) ? bk : bv;
      float bval = bb[nn];
      if (wi == 2) {  // V: write transposed [B,H,D,T], 4 consecutive t -> uint2
#pragma unroll
        for (int mt = 0; mt < 4; ++mt) {
          int m = m0 + wm + mt * 16 + lg * 4;
          int mb = m >> 11, t = m & 2047;
          unsigned lo = cvtpk(acc[mt][nt][0] + bval, acc[mt][nt][1] + bval);
          unsigned hi = cvtpk(acc[mt][nt][2] + bval, acc[mt][nt][3] + bval);
          *(uint2*)&vd[((size_t)(mb * 16 + h) * 64 + d) * 2048 + t] =
              make_uint2(lo, hi);
        }
      } else {
        u16* dst = (wi == 0) ? qd : kd;
#pragma unroll
        for (int mt = 0; mt < 4; ++mt) {
#pragma unroll
          for (int i = 0; i < 4; ++i) {
            int m = m0 + wm + mt * 16 + lg * 4 + i;
            int mb = m >> 11, t = m & 2047;
            dst[((size_t)(mb * 16 + h) * 2048 + t) * 64 + d] =
                f2bf(acc[mt][nt][i] + bval);
          }
        }
      }
    }
  } else {
#pragma unroll
    for (int nt = 0; nt < 4; ++nt) {
      int n = n0 + wn + nt * 16 + l15;
      float bval = bias1[n];
#pragma unroll
      for (int mt = 0; mt < 4; ++mt) {
#pragma unroll
        for (int i = 0; i < 4; ++i) {
          int m = m0 + wm + mt * 16 + lg * 4 + i;
          outf[(size_t)m * 1024 + n] = acc[mt][nt][i] + bval;
        }
      }
    }
  }
}

// ---------------- causal flash attention, swapped-operand MFMA ----------------
// 1024 blocks, one 64-row q-tile each (4 waves x 16 rows), longest-first.
// head = flat&31 keeps flat%8 == head%8 -> 4 heads/XCD, K+V^T L2-resident.
// All staging pointers advance by constant stride per tile; all LDS addresses
// hoisted: row&7 == l15&7 makes the XOR swizzle loop-invariant, so K, V and P
// reads share two base ints and nt*2048 immediates.
__global__ __launch_bounds__(256, 4) void fattn_kernel(const u16* __restrict__ qb,
                                                       const u16* __restrict__ kb,
                                                       const u16* __restrict__ vt,
                                                       u16* __restrict__ y) {
  __shared__ u16 Klds[2 * 4096];
  __shared__ u16 Vlds[2 * 4096];   // V^T: [d][kv], swizzled
  __shared__ u16 Plds[4 * 1024];
  int tid = threadIdx.x, lane = tid & 63, w = tid >> 6;
  int l15 = lane & 15, lg = lane >> 4;
  int flat = blockIdx.x;
  int bh = flat & 31;
  int qt = 31 - (flat >> 5);          // longest-first dispatch
  size_t base = (size_t)bh * 2048 * 64;
  int mb = bh >> 4, h = bh & 15;
  const float SC = 0.125f * 1.44269504088896340736f;  // fold /sqrt(64), log2(e)
  const float NINF = -__builtin_inff();

  // ---- hoisted staging geometry (advance per tile: K +4096, V +64 elem) ----
  int r0 = tid >> 3, c0 = ((tid & 7) * 8) ^ ((r0 & 7) << 3);
  int r1 = (256 + tid) >> 3, c1 = ((tid & 7) * 8) ^ ((r1 & 7) << 3);
  const u16* pK0 = kb + base + (size_t)r0 * 64 + c0;
  const u16* pK1 = kb + base + (size_t)r1 * 64 + c1;
  const u16* pV0 = vt + base + (size_t)r0 * 2048 + c0;
  const u16* pV1 = vt + base + (size_t)r1 * 2048 + c1;
  int dk0 = w * 512, dk1 = (256 + w * 64) * 8;   // LDS dest offsets (u16)
  // ---- hoisted LDS read bases (bytes); shared by K, V, P reads ----
  int kx = (l15 & 7) << 4;
  int rb0 = l15 * 128 + ((lg * 16) ^ kx);
  int rb1 = l15 * 128 + ((64 + lg * 16) ^ kx);
  char* pbase = (char*)Plds + w * 2048;
  int pw0 = l15 * 128 + ((lg * 8) ^ kx);
  int pw1 = l15 * 128 + ((32 + lg * 8) ^ kx);
  int pw2 = l15 * 128 + ((64 + lg * 8) ^ kx);
  int pw3 = l15 * 128 + ((96 + lg * 8) ^ kx);

  int qw = qt * 64 + w * 16;
  int qr = qw + l15;
  short8 qf[2];
#pragma unroll
  for (int kk = 0; kk < 2; ++kk)
    qf[kk] = *(const short8*)&qb[base + (size_t)qr * 64 + kk * 32 + lg * 8];
  f32x4 o[4] = {};
  float mrow = NINF, lrow = 0.f;
  {  // prologue stage tile 0 into buf 0
    gload16(pK0, Klds + dk0); gload16(pK1, Klds + dk1);
    gload16(pV0, Vlds + dk0); gload16(pV1, Vlds + dk1);
    pK0 += 4096; pK1 += 4096; pV0 += 64; pV1 += 64;
  }
  int cb = 0;
  int ntiles = qt + 1;
  for (int j = 0; j < ntiles; ++j) {
    __syncthreads();  // compiler drains vmcnt before barrier: buf[cb] ready
    if (j + 1 < ntiles) {  // prefetch next tile into cb^1
      u16* kd_ = Klds + (cb ^ 1) * 4096;
      u16* vd_ = Vlds + (cb ^ 1) * 4096;
      gload16(pK0, kd_ + dk0); gload16(pK1, kd_ + dk1);
      gload16(pV0, vd_ + dk0); gload16(pV1, vd_ + dk1);
      pK0 += 4096; pK1 += 4096; pV0 += 64; pV1 += 64;
    }
    const char* kl = (const char*)Klds + cb * 8192;
    const char* vl = (const char*)Vlds + cb * 8192;
    // S^T = K Q^T  (swapped operands)
    f32x4 s[4] = {};
    __builtin_amdgcn_s_setprio(1);
#pragma unroll
    for (int kk = 0; kk < 2; ++kk) {
      int o_ = kk ? rb1 : rb0;
      short8 ka[4];
#pragma unroll
      for (int nt = 0; nt < 4; ++nt)
        ka[nt] = *(const short8*)(kl + o_ + nt * 2048);
#pragma unroll
      for (int nt = 0; nt < 4; ++nt)
        s[nt] = __builtin_amdgcn_mfma_f32_16x16x32_bf16(ka[nt], qf[kk], s[nt], 0, 0, 0);
    }
    __builtin_amdgcn_s_setprio(0);
    // masked raw scores (scale folded into the exp FMA)
    float rs[16];
    if (j == qt) {
      int k0 = j * 64;
#pragma unroll
      for (int nt = 0; nt < 4; ++nt)
#pragma unroll
        for (int i = 0; i < 4; ++i) {
          int ka_ = k0 + nt * 16 + lg * 4 + i;
          rs[nt * 4 + i] = (ka_ > qr) ? NINF : s[nt][i];
        }
    } else {
#pragma unroll
      for (int nt = 0; nt < 4; ++nt)
#pragma unroll
        for (int i = 0; i < 4; ++i) rs[nt * 4 + i] = s[nt][i];
    }
    // per-lane partial max; ballot over partials == ballot over full max
    float rmax = fmaxf(
        fmaxf(fmaxf(fmaxf(rs[0], rs[1]), fmaxf(rs[2], rs[3])),
              fmaxf(fmaxf(rs[4], rs[5]), fmaxf(rs[6], rs[7]))),
        fmaxf(fmaxf(fmaxf(rs[8], rs[9]), fmaxf(rs[10], rs[11])),
              fmaxf(fmaxf(rs[12], rs[13]), fmaxf(rs[14], rs[15]))));
    float tmax = rmax * SC;
    if (!__all(tmax <= mrow + 8.f)) {  // rare: full reduce + rescale
      float t2 = fmaxf(tmax, __shfl_xor(tmax, 16));
      t2 = fmaxf(t2, __shfl_xor(t2, 32));
      float vmax = fmaxf(t2, mrow);
      float scale = exp2f(mrow - vmax);
      mrow = vmax;
      lrow *= scale;
#pragma unroll
      for (int dn = 0; dn < 4; ++dn) o[dn] *= scale;
    }
    float p[16];
#pragma unroll
    for (int u = 0; u < 16; ++u) p[u] = exp2f(fmaf(rs[u], SC, -mrow));
    float pr0 = ((p[0] + p[1]) + (p[2] + p[3])) + ((p[4] + p[5]) + (p[6] + p[7]));
    float pr1 = ((p[8] + p[9]) + (p[10] + p[11])) + ((p[12] + p[13]) + (p[14] + p[15]));
    lrow += pr0 + pr1;  // per-lane partial; reduced after the loop
    // P[q][k] -> LDS, packed b64 (4 consecutive k per write)
    *(uint2*)(pbase + pw0) = make_uint2(cvtpk(p[0], p[1]), cvtpk(p[2], p[3]));
    *(uint2*)(pbase + pw1) = make_uint2(cvtpk(p[4], p[5]), cvtpk(p[6], p[7]));
    *(uint2*)(pbase + pw2) = make_uint2(cvtpk(p[8], p[9]), cvtpk(p[10], p[11]));
    *(uint2*)(pbase + pw3) = make_uint2(cvtpk(p[12], p[13]), cvtpk(p[14], p[15]));
    // O^T += V^T P^T  (swapped operands)
    __builtin_amdgcn_s_setprio(1);
#pragma unroll
    for (int kk = 0; kk < 2; ++kk) {
      int o_ = kk ? rb1 : rb0;
      short8 ap = *(const short8*)(pbase + o_);
#pragma unroll
      for (int dn = 0; dn < 4; ++dn) {
        short8 bv_ = *(const short8*)(vl + o_ + dn * 2048);
        o[dn] = __builtin_amdgcn_mfma_f32_16x16x32_bf16(bv_, ap, o[dn], 0, 0, 0);
      }
    }
    __builtin_amdgcn_s_setprio(0);
    cb ^= 1;
  }
  // combine lrow partials across the 4 lane-groups of each q-row
  lrow += __shfl_xor(lrow, 16);
  lrow += __shfl_xor(lrow, 32);
  float inv = 1.f / lrow;
  size_t rb = ((size_t)(mb * 2048 + qr)) * 1024 + (size_t)h * 64;
#pragma unroll
  for (int dn = 0; dn < 4; ++dn) {
    unsigned lo = cvtpk(o[dn][0] * inv, o[dn][1] * inv);
    unsigned hi = cvtpk(o[dn][2] * inv, o[dn][3] * inv);
    *(uint2*)&y[rb + dn * 16 + lg * 4] = make_uint2(lo, hi);
  }
}

extern "C" void kernel_launch(void* const* d_in, const int* in_sizes, int n_in,
                              void* d_out, int out_size, void* d_ws, size_t ws_size,
                              hipStream_t stream) {
  const float* x  = (const float*)d_in[0];
  const float* Wq = (const float*)d_in[1];
  const float* bq = (const float*)d_in[2];
  const float* Wk = (const float*)d_in[3];
  const float* bk = (const float*)d_in[4];
  const float* Wv = (const float*)d_in[5];
  const float* bv = (const float*)d_in[6];
  const float* Wp = (const float*)d_in[7];
  const float* bp = (const float*)d_in[8];
  float* out = (float*)d_out;
  char* ws = (char*)d_ws;
  u16* xb   = (u16*)(ws);
  u16* wt   = (u16*)(ws + ((size_t)8 << 20));
  u16* qbuf = (u16*)(ws + ((size_t)16 << 20));
  u16* kbuf = (u16*)(ws + ((size_t)24 << 20));
  u16* vtb  = (u16*)(ws + ((size_t)32 << 20));  // V^T written by QKV epilogue
  u16* ybuf = (u16*)(ws + ((size_t)40 << 20));

  prep_kernel<<<dim3(3072), dim3(256), 0, stream>>>(x, Wq, Wk, Wv, Wp, xb, wt);
  // QKV: M=4096 (GM=32), N=3072 (GN=24); per-XCD region 8x12 blocks
  gemm128_kernel<0><<<dim3(768), dim3(256), 0, stream>>>(
      xb, wt, 1024, 32, 24, 8, 12,
      qbuf, kbuf, vtb, bq, bk, bv, (float*)nullptr, (const float*)nullptr);
  fattn_kernel<<<dim3(1024), dim3(256), 0, stream>>>(qbuf, kbuf, vtb, ybuf);
  // proj: M=4096 (GM=32), N=1024 (GN=8); per-XCD region 8x4 blocks
  gemm128_kernel<1><<<dim3(256), dim3(256), 0, stream>>>(
      ybuf, wt + (size_t)3 * 1024 * 1024, 1024, 32, 8, 8, 4,
      (u16*)nullptr, (u16*)nullptr, (u16*)nullptr,
      (const float*)nullptr, (const float*)nullptr, (const float*)nullptr, out, bp);
  (void)in_sizes; (void)n_in; (void)out_size; (void)ws_size;
}